// Round 4
// baseline (486.862 us; speedup 1.0000x reference)
//
#include <hip/hip_runtime.h>
#include <hip/hip_bf16.h>
#include <stdint.h>

// Problem constants (from reference)
#define H   128
#define NM  5000
#define NO  100000
#define EA  1000000
#define EC  500000
#define ET  1000000
#define EL  500000

typedef __hip_bfloat16 bf16;

// sums layout (float offsets)
#define SA_OFF 0      // 8 copies x 128 : sum_e relu(...) for assign
#define SC_OFF 1024   // 8 copies x 128 : same for completion
#define XM_OFF 2048   // 8 copies x 4   : sum over nodes of x_m components
#define XO_OFF 2080   // 8 copies x 4   : sum over nodes of x_o components
#define TV_OFF 2112   // 8 copies x 8   : [0..3]=sum w*x_o, [4]=sum w   (type_valid)
#define LG_OFF 2176   // 8 copies x 8   : same for logical
#define SUMS_FLOATS 2240

struct Par {
    const void *x_m, *x_o, *ea_a, *ea_c;
    const int *ei_a, *ei_c, *ei_tv, *ei_log;
    const void *Wm, *bm, *Wo, *bo;
    const void *Wn_a, *bn_a, *We_a, *be_a;
    const void *Wn_c, *bn_c, *We_c, *be_c;
    const void *Wl_tv, *bl_tv, *Wr_tv, *Wl_log, *bl_log, *Wr_log;
    int *cnt_m, *cnt_o;
    float *sums;
    const int *flag;
    void *out;
};

// ---- dtype-flexible load: flag-selected fp32 vs bf16 ----
template<bool ISF32>
__device__ __forceinline__ float ldf(const void* p, int i) {
    if constexpr (ISF32) return ((const float*)p)[i];
    else                 return __bfloat162float(((const bf16*)p)[i]);
}

__device__ __forceinline__ float wred(float v) {
#pragma unroll
    for (int o = 32; o; o >>= 1) v += __shfl_down(v, o, 64);
    return v;
}

// ---- zero scratch ----
__global__ void zero_kernel(int* __restrict__ p, int n) {
    int i = blockIdx.x * blockDim.x + threadIdx.x;
    if (i < n) p[i] = 0;
}

// ---- dtype probe: fp32 viewed as u16 contains exponent-0xFF patterns ----
__global__ void detect_kernel(const uint16_t* __restrict__ x, int n, int* __restrict__ flag) {
    int i = blockIdx.x * blockDim.x + threadIdx.x;
    if (i < n) {
        if (((x[i] >> 7) & 0xFF) == 0xFF) atomicOr(flag, 1);
    }
}

// ---- counts: cnt_m via LDS histogram (5000 bins); cnt_o direct atomics ----
#define CB_M 32
#define CB_O 128
__global__ __launch_bounds__(256) void counts_kernel(const Par p) {
    const int b = blockIdx.x;
    if (b < CB_M) {
        __shared__ int hist[NM];
        for (int i = threadIdx.x; i < NM; i += 256) hist[i] = 0;
        __syncthreads();
        const int* __restrict__ dst = p.ei_tv + ET;
        const int chunk = (ET + CB_M - 1) / CB_M;
        const int e0 = b * chunk;
        int e1 = e0 + chunk; if (e1 > ET) e1 = ET;
        for (int i = e0 + threadIdx.x; i < e1; i += 256)
            atomicAdd(&hist[dst[i]], 1);
        __syncthreads();
        for (int i = threadIdx.x; i < NM; i += 256) {
            const int v = hist[i];
            if (v) atomicAdd(&p.cnt_m[i], v);
        }
    } else {
        const int* __restrict__ dst = p.ei_log + EL;
        const int stride = CB_O * 256;
        for (int i = (b - CB_M) * 256 + threadIdx.x; i < EL; i += stride)
            atomicAdd(&p.cnt_o[dst[i]], 1);
    }
}

// ---- GINE edge sum, h recomputed from x on the fly ----
// Sout += sum_e relu(x[src_e]@Wx + bx + ea_e@We + be), per-channel.
// lane owns channels {2l, 2l+1}; contiguous edge chunk per wave.
template<int ED, int FIN, bool ISF32>
__device__ __forceinline__ void gine_body(
    const int* __restrict__ src, const void* __restrict__ ea,
    const void* __restrict__ x, const void* __restrict__ We,
    const void* __restrict__ be, const void* __restrict__ Wx,
    const void* __restrict__ bx, float* __restrict__ Sout, int E)
{
    const int lane = threadIdx.x & 63;
    const int c0 = 2 * lane, c1 = c0 + 1;
    float we0[ED], we1[ED], wx0[FIN], wx1[FIN];
#pragma unroll
    for (int k = 0; k < ED; ++k) {
        we0[k] = ldf<ISF32>(We, k * H + c0);
        we1[k] = ldf<ISF32>(We, k * H + c1);
    }
#pragma unroll
    for (int k = 0; k < FIN; ++k) {
        wx0[k] = ldf<ISF32>(Wx, k * H + c0);
        wx1[k] = ldf<ISF32>(Wx, k * H + c1);
    }
    const float b0 = ldf<ISF32>(be, c0) + ldf<ISF32>(bx, c0);
    const float b1 = ldf<ISF32>(be, c1) + ldf<ISF32>(bx, c1);

    const int wv = blockIdx.x * 4 + (threadIdx.x >> 6);
    const int nw = gridDim.x * 4;
    const int chunk = (E + nw - 1) / nw;
    int e0 = wv * chunk;
    int e1 = e0 + chunk; if (e1 > E) e1 = E; if (e0 > E) e0 = E;

    float acc0 = 0.f, acc1 = 0.f;
#pragma unroll 2
    for (int e = e0; e < e1; ++e) {
        const int s = src[e];
        float m0 = b0, m1 = b1;
        if constexpr (FIN == 4 && ISF32) {
            const float4 xv = ((const float4*)x)[s];
            m0 = fmaf(xv.x, wx0[0], m0); m1 = fmaf(xv.x, wx1[0], m1);
            m0 = fmaf(xv.y, wx0[1], m0); m1 = fmaf(xv.y, wx1[1], m1);
            m0 = fmaf(xv.z, wx0[2], m0); m1 = fmaf(xv.z, wx1[2], m1);
            m0 = fmaf(xv.w, wx0[3], m0); m1 = fmaf(xv.w, wx1[3], m1);
        } else {
#pragma unroll
            for (int k = 0; k < FIN; ++k) {
                const float xk = ldf<ISF32>(x, s * FIN + k);
                m0 = fmaf(xk, wx0[k], m0);
                m1 = fmaf(xk, wx1[k], m1);
            }
        }
#pragma unroll
        for (int k = 0; k < ED; ++k) {
            const float a = ldf<ISF32>(ea, e * ED + k);
            m0 = fmaf(a, we0[k], m0);
            m1 = fmaf(a, we1[k], m1);
        }
        acc0 += fmaxf(m0, 0.f);
        acc1 += fmaxf(m1, 0.f);
    }
    __shared__ float r0[256], r1[256];
    r0[threadIdx.x] = acc0; r1[threadIdx.x] = acc1;
    __syncthreads();
    if (threadIdx.x < 64) {
        const int l = threadIdx.x;
        float s0 = r0[l] + r0[l + 64] + r0[l + 128] + r0[l + 192];
        float s1 = r1[l] + r1[l + 64] + r1[l + 128] + r1[l + 192];
        float* d = &Sout[(blockIdx.x & 7) * H + 2 * l];
        atomicAdd(d, s0);
        atomicAdd(d + 1, s1);
    }
}

__global__ __launch_bounds__(256) void gine_a_kernel(const Par p) {
    if (*p.flag) gine_body<3, 3, true >(p.ei_a, p.ea_a, p.x_m, p.We_a, p.be_a, p.Wm, p.bm, p.sums + SA_OFF, EA);
    else         gine_body<3, 3, false>(p.ei_a, p.ea_a, p.x_m, p.We_a, p.be_a, p.Wm, p.bm, p.sums + SA_OFF, EA);
}

__global__ __launch_bounds__(256) void gine_c_kernel(const Par p) {
    if (*p.flag) gine_body<1, 4, true >(p.ei_c, p.ea_c, p.x_o, p.We_c, p.be_c, p.Wo, p.bo, p.sums + SC_OFF, EC);
    else         gine_body<1, 4, false>(p.ei_c, p.ea_c, p.x_o, p.We_c, p.be_c, p.Wo, p.bo, p.sums + SC_OFF, EC);
}

// ---- component sums of x over nodes ----
template<int FIN, bool ISF32>
__device__ __forceinline__ void mean_body(
    const void* __restrict__ x, float* __restrict__ out, int N, int relblk, int nblk)
{
    const int stride = nblk * 256;
    float acc[FIN];
#pragma unroll
    for (int k = 0; k < FIN; ++k) acc[k] = 0.f;
    for (int n = relblk * 256 + threadIdx.x; n < N; n += stride) {
        if constexpr (FIN == 4 && ISF32) {
            const float4 xv = ((const float4*)x)[n];
            acc[0] += xv.x; acc[1] += xv.y; acc[2] += xv.z; acc[3] += xv.w;
        } else {
#pragma unroll
            for (int k = 0; k < FIN; ++k) acc[k] += ldf<ISF32>(x, n * FIN + k);
        }
    }
#pragma unroll
    for (int k = 0; k < FIN; ++k) {
        float v = wred(acc[k]);
        if ((threadIdx.x & 63) == 0)
            atomicAdd(&out[(blockIdx.x & 7) * 4 + k], v);
    }
}

__global__ __launch_bounds__(256) void means_kernel(const Par p) {
    const bool f32 = (*p.flag) != 0;
    if (blockIdx.x < 8) {
        if (f32) mean_body<3, true >(p.x_m, p.sums + XM_OFF, NM, blockIdx.x, 8);
        else     mean_body<3, false>(p.x_m, p.sums + XM_OFF, NM, blockIdx.x, 8);
    } else {
        if (f32) mean_body<4, true >(p.x_o, p.sums + XO_OFF, NO, blockIdx.x - 8, 40);
        else     mean_body<4, false>(p.x_o, p.sums + XO_OFF, NO, blockIdx.x - 8, 40);
    }
}

// ---- SAGE direct edge reduction: S[0..3] += x_o[src]*w, S[4] += w; w=1/max(cnt[dst],1)
template<bool ISF32>
__device__ __forceinline__ void sage_body(
    const void* __restrict__ x, const int* __restrict__ src,
    const int* __restrict__ dst, const int* __restrict__ cnt,
    float* __restrict__ S, int E)
{
    const int chunk = (E + gridDim.x - 1) / gridDim.x;
    const int e0 = blockIdx.x * chunk;
    int e1 = e0 + chunk; if (e1 > E) e1 = E;
    float a0 = 0.f, a1 = 0.f, a2 = 0.f, a3 = 0.f, aw = 0.f;
    for (int e = e0 + threadIdx.x; e < e1; e += 256) {
        const int s = src[e];
        const int c = cnt[dst[e]];
        const float inv = __builtin_amdgcn_rcpf((float)(c > 0 ? c : 1));
        float xv0, xv1, xv2, xv3;
        if constexpr (ISF32) {
            const float4 t = ((const float4*)x)[s];
            xv0 = t.x; xv1 = t.y; xv2 = t.z; xv3 = t.w;
        } else {
            xv0 = ldf<ISF32>(x, s * 4 + 0); xv1 = ldf<ISF32>(x, s * 4 + 1);
            xv2 = ldf<ISF32>(x, s * 4 + 2); xv3 = ldf<ISF32>(x, s * 4 + 3);
        }
        a0 = fmaf(inv, xv0, a0); a1 = fmaf(inv, xv1, a1);
        a2 = fmaf(inv, xv2, a2); a3 = fmaf(inv, xv3, a3);
        aw += inv;
    }
    float* d = &S[(blockIdx.x & 7) * 8];
    float v;
    v = wred(a0); if ((threadIdx.x & 63) == 0) atomicAdd(&d[0], v);
    v = wred(a1); if ((threadIdx.x & 63) == 0) atomicAdd(&d[1], v);
    v = wred(a2); if ((threadIdx.x & 63) == 0) atomicAdd(&d[2], v);
    v = wred(a3); if ((threadIdx.x & 63) == 0) atomicAdd(&d[3], v);
    v = wred(aw); if ((threadIdx.x & 63) == 0) atomicAdd(&d[4], v);
}

__global__ __launch_bounds__(256) void sage_tv_kernel(const Par p) {
    if (*p.flag) sage_body<true >(p.x_o, p.ei_tv, p.ei_tv + ET, p.cnt_m, p.sums + TV_OFF, ET);
    else         sage_body<false>(p.x_o, p.ei_tv, p.ei_tv + ET, p.cnt_m, p.sums + TV_OFF, ET);
}

__global__ __launch_bounds__(256) void sage_log_kernel(const Par p) {
    if (*p.flag) sage_body<true >(p.x_o, p.ei_log, p.ei_log + EL, p.cnt_o, p.sums + LG_OFF, EL);
    else         sage_body<false>(p.x_o, p.ei_log, p.ei_log + EL, p.cnt_o, p.sums + LG_OFF, EL);
}

// ---- final: reconstruct means, five 128x128 mat-vecs, write 256 outputs ----
template<bool ISF32>
__device__ __forceinline__ void final_body(const Par p) {
    __shared__ float vtv[H], vmhm[H], va[H], vc[H], vlog[H], vmho[H];
    const float* S = p.sums;
    const int t = threadIdx.x;
    if (t < H) {
        float sa = 0.f, sc = 0.f;
        float xm[3] = {0, 0, 0}, xo[4] = {0, 0, 0, 0};
        float twx[4] = {0, 0, 0, 0}, lwx[4] = {0, 0, 0, 0};
        float tsw = 0.f, lsw = 0.f;
#pragma unroll
        for (int cp = 0; cp < 8; ++cp) {
            sa += S[SA_OFF + cp * H + t];
            sc += S[SC_OFF + cp * H + t];
#pragma unroll
            for (int k = 0; k < 3; ++k) xm[k] += S[XM_OFF + cp * 4 + k];
#pragma unroll
            for (int k = 0; k < 4; ++k) {
                xo[k]  += S[XO_OFF + cp * 4 + k];
                twx[k] += S[TV_OFF + cp * 8 + k];
                lwx[k] += S[LG_OFF + cp * 8 + k];
            }
            tsw += S[TV_OFF + cp * 8 + 4];
            lsw += S[LG_OFF + cp * 8 + 4];
        }
        float mhm = ldf<ISF32>(p.bm, t);
#pragma unroll
        for (int k = 0; k < 3; ++k)
            mhm = fmaf(xm[k] * (1.f / NM), ldf<ISF32>(p.Wm, k * H + t), mhm);
        float mho = ldf<ISF32>(p.bo, t);
#pragma unroll
        for (int k = 0; k < 4; ++k)
            mho = fmaf(xo[k] * (1.f / NO), ldf<ISF32>(p.Wo, k * H + t), mho);
        float tv = tsw * ldf<ISF32>(p.bo, t);
        float lg = lsw * ldf<ISF32>(p.bo, t);
#pragma unroll
        for (int k = 0; k < 4; ++k) {
            tv = fmaf(twx[k], ldf<ISF32>(p.Wo, k * H + t), tv);
            lg = fmaf(lwx[k], ldf<ISF32>(p.Wo, k * H + t), lg);
        }
        vmhm[t] = mhm;
        vmho[t] = mho;
        vtv[t]  = tv * (1.f / NM);
        vlog[t] = lg * (1.f / NO);
        va[t] = sa * (1.f / NO) + mho;
        vc[t] = sc * (1.f / NO) + mho;
    }
    __syncthreads();
    float res; int oidx;
    if (t < H) {
        float acc = ldf<ISF32>(p.bl_tv, t);
        for (int k = 0; k < H; ++k) {
            acc = fmaf(vtv[k],  ldf<ISF32>(p.Wl_tv, k * H + t), acc);
            acc = fmaf(vmhm[k], ldf<ISF32>(p.Wr_tv, k * H + t), acc);
        }
        res = acc; oidx = t;
    } else {
        const int c = t - H;
        float acc = ldf<ISF32>(p.bn_a, c) + ldf<ISF32>(p.bn_c, c) + ldf<ISF32>(p.bl_log, c);
        for (int k = 0; k < H; ++k) {
            acc = fmaf(va[k],   ldf<ISF32>(p.Wn_a, k * H + c), acc);
            acc = fmaf(vc[k],   ldf<ISF32>(p.Wn_c, k * H + c), acc);
            acc = fmaf(vlog[k], ldf<ISF32>(p.Wl_log, k * H + c), acc);
            acc = fmaf(vmho[k], ldf<ISF32>(p.Wr_log, k * H + c), acc);
        }
        res = acc * (1.f / 3.f); oidx = H + c;
    }
    if constexpr (ISF32) ((float*)p.out)[oidx] = res;
    else                 ((bf16*)p.out)[oidx] = __float2bfloat16(res);
}

__global__ __launch_bounds__(256) void final_kernel(const Par p) {
    if (*p.flag) final_body<true >(p);
    else         final_body<false>(p);
}

extern "C" void kernel_launch(void* const* d_in, const int* in_sizes, int n_in,
                              void* d_out, int out_size, void* d_ws, size_t ws_size,
                              hipStream_t stream) {
    char* ws = (char*)d_ws;
    Par p;
    p.x_m   = d_in[0];  p.x_o   = d_in[1];
    p.ea_a  = d_in[2];  p.ea_c  = d_in[3];
    p.ei_a  = (const int*)d_in[4];
    p.ei_c  = (const int*)d_in[5];
    p.ei_tv = (const int*)d_in[6];
    p.ei_log= (const int*)d_in[7];
    p.Wm = d_in[8];  p.bm = d_in[9];  p.Wo = d_in[10]; p.bo = d_in[11];
    p.Wn_a = d_in[12]; p.bn_a = d_in[13]; p.We_a = d_in[14]; p.be_a = d_in[15];
    p.Wn_c = d_in[16]; p.bn_c = d_in[17]; p.We_c = d_in[18]; p.be_c = d_in[19];
    p.Wl_tv = d_in[20]; p.bl_tv = d_in[21]; p.Wr_tv = d_in[22];
    p.Wl_log = d_in[23]; p.bl_log = d_in[24]; p.Wr_log = d_in[25];

    // Workspace layout (bytes):
    //   [0,      20000)   cnt_m int[NM]
    //   [20000,  420000)  cnt_o int[NO]
    //   [420000, 428960)  sums  float[2240]
    //   [428960, 428964)  flag  int
    p.cnt_m = (int*)(ws);
    p.cnt_o = (int*)(ws + 20000);
    p.sums  = (float*)(ws + 420000);
    int* flag = (int*)(ws + 428960);
    p.flag  = flag;
    p.out   = d_out;

    // zero all accumulators + flag: 428964 bytes -> 107241 ints
    const int nzero = 107241;
    zero_kernel<<<(nzero + 255) / 256, 256, 0, stream>>>((int*)ws, nzero);

    // dtype probe on x_machine (first 15000 u16 — in-bounds under either dtype)
    detect_kernel<<<59, 256, 0, stream>>>((const uint16_t*)d_in[0], 15000, flag);

    counts_kernel<<<CB_M + CB_O, 256, 0, stream>>>(p);
    gine_a_kernel<<<2048, 256, 0, stream>>>(p);
    gine_c_kernel<<<1024, 256, 0, stream>>>(p);
    means_kernel<<<48, 256, 0, stream>>>(p);
    sage_tv_kernel<<<1024, 256, 0, stream>>>(p);
    sage_log_kernel<<<512, 256, 0, stream>>>(p);
    final_kernel<<<1, 256, 0, stream>>>(p);
}

// Round 5
// 346.065 us; speedup vs baseline: 1.4069x; 1.4069x over previous
//
#include <hip/hip_runtime.h>
#include <hip/hip_bf16.h>
#include <stdint.h>

// Problem constants (from reference)
#define H   128
#define NM  5000
#define NO  100000
#define EA  1000000
#define EC  500000
#define ET  1000000
#define EL  500000

typedef __hip_bfloat16 bf16;

// K1 block partition: counts_m | counts_o | gine_a | gine_c | means
#define B1_CM 32
#define B1_CO 256
#define B1_GA 512
#define B1_GC 256
#define B1_MN 48
#define K1_BLOCKS (B1_CM + B1_CO + B1_GA + B1_GC + B1_MN)
// K2 block partition: sage_tv | sage_log
#define B2_TV 256
#define B2_LG 256

struct Par {
    const void *x_m, *x_o, *ea_a, *ea_c;
    const int *ei_a, *ei_c, *ei_tv, *ei_log;
    const void *Wm, *bm, *Wo, *bo;
    const void *Wn_a, *bn_a, *We_a, *be_a;
    const void *Wn_c, *bn_c, *We_c, *be_c;
    const void *Wl_tv, *bl_tv, *Wr_tv, *Wl_log, *bl_log, *Wr_log;
    int *cnt_m, *cnt_o;
    float *part_a, *part_c, *part_tv, *part_lg, *part_mn;
    const int *flag;
    void *out;
};

// ---- dtype-flexible loads ----
template<bool ISF32>
__device__ __forceinline__ float ldf(const void* p, int i) {
    if constexpr (ISF32) return ((const float*)p)[i];
    else                 return __bfloat162float(((const bf16*)p)[i]);
}

__device__ __forceinline__ float bflo(uint32_t v) {
    union { uint32_t u; float f; } c; c.u = v << 16; return c.f;
}
__device__ __forceinline__ float bfhi(uint32_t v) {
    union { uint32_t u; float f; } c; c.u = v & 0xFFFF0000u; return c.f;
}

// 4-wide row load (row of 4 elements)
template<bool ISF32>
__device__ __forceinline__ float4 ld4(const void* p, int row) {
    if constexpr (ISF32) return ((const float4*)p)[row];
    else {
        const uint2 t = ((const uint2*)p)[row];
        float4 r; r.x = bflo(t.x); r.y = bfhi(t.x); r.z = bflo(t.y); r.w = bfhi(t.y);
        return r;
    }
}

__device__ __forceinline__ float wred(float v) {
#pragma unroll
    for (int o = 32; o; o >>= 1) v += __shfl_down(v, o, 64);
    return v;
}

// ---- zero scratch ----
__global__ void zero_kernel(int* __restrict__ p, int n) {
    int i = blockIdx.x * blockDim.x + threadIdx.x;
    if (i < n) p[i] = 0;
}

// ---- dtype probe: fp32 viewed as u16 contains exponent-0xFF patterns ----
__global__ void detect_kernel(const uint16_t* __restrict__ x, int n, int* __restrict__ flag) {
    int i = blockIdx.x * blockDim.x + threadIdx.x;
    if (i < n) {
        if (((x[i] >> 7) & 0xFF) == 0xFF) atomicOr(flag, 1);
    }
}

// ---- counts: cnt_m via LDS histogram; cnt_o direct spread atomics ----
__device__ __forceinline__ void count_m_body(
    const int* __restrict__ dst, int* __restrict__ cnt, int relb, int* hist)
{
    for (int i = threadIdx.x; i < NM; i += 256) hist[i] = 0;
    __syncthreads();
    const int chunk = (ET + B1_CM - 1) / B1_CM;
    const int e0 = relb * chunk;
    int e1 = e0 + chunk; if (e1 > ET) e1 = ET;
    for (int i = e0 + threadIdx.x; i < e1; i += 256)
        atomicAdd(&hist[dst[i]], 1);
    __syncthreads();
    for (int i = threadIdx.x; i < NM; i += 256) {
        const int v = hist[i];
        if (v) atomicAdd(&cnt[i], v);
    }
}

__device__ __forceinline__ void count_o_body(
    const int* __restrict__ dst, int* __restrict__ cnt, int relb)
{
    const int stride = B1_CO * 256;
    for (int i = relb * 256 + threadIdx.x; i < EL; i += stride)
        atomicAdd(&cnt[dst[i]], 1);
}

// ---- GINE edge sum, h recomputed from x; block partial -> plain store ----
template<int ED, int FIN, bool ISF32>
__device__ __forceinline__ void gine_body(
    const int* __restrict__ src, const void* __restrict__ ea,
    const void* __restrict__ x, const void* __restrict__ We,
    const void* __restrict__ be, const void* __restrict__ Wx,
    const void* __restrict__ bx, float* __restrict__ part,
    int E, int relb, int nblk, float* r0, float* r1)
{
    const int lane = threadIdx.x & 63;
    const int c0 = 2 * lane, c1 = c0 + 1;
    float we0[ED], we1[ED], wx0[FIN], wx1[FIN];
#pragma unroll
    for (int k = 0; k < ED; ++k) {
        we0[k] = ldf<ISF32>(We, k * H + c0);
        we1[k] = ldf<ISF32>(We, k * H + c1);
    }
#pragma unroll
    for (int k = 0; k < FIN; ++k) {
        wx0[k] = ldf<ISF32>(Wx, k * H + c0);
        wx1[k] = ldf<ISF32>(Wx, k * H + c1);
    }
    const float b0 = ldf<ISF32>(be, c0) + ldf<ISF32>(bx, c0);
    const float b1 = ldf<ISF32>(be, c1) + ldf<ISF32>(bx, c1);

    const int wv = relb * 4 + (threadIdx.x >> 6);
    const int nw = nblk * 4;
    const int chunk = (E + nw - 1) / nw;
    int e0 = wv * chunk;
    int e1 = e0 + chunk; if (e1 > E) e1 = E; if (e0 > E) e0 = E;

    float acc0 = 0.f, acc1 = 0.f;
#pragma unroll 2
    for (int e = e0; e < e1; ++e) {
        const int s = src[e];
        float m0 = b0, m1 = b1;
        if constexpr (FIN == 4) {
            const float4 xv = ld4<ISF32>(x, s);
            m0 = fmaf(xv.x, wx0[0], m0); m1 = fmaf(xv.x, wx1[0], m1);
            m0 = fmaf(xv.y, wx0[1], m0); m1 = fmaf(xv.y, wx1[1], m1);
            m0 = fmaf(xv.z, wx0[2], m0); m1 = fmaf(xv.z, wx1[2], m1);
            m0 = fmaf(xv.w, wx0[3], m0); m1 = fmaf(xv.w, wx1[3], m1);
        } else {
#pragma unroll
            for (int k = 0; k < FIN; ++k) {
                const float xk = ldf<ISF32>(x, s * FIN + k);
                m0 = fmaf(xk, wx0[k], m0);
                m1 = fmaf(xk, wx1[k], m1);
            }
        }
#pragma unroll
        for (int k = 0; k < ED; ++k) {
            const float a = ldf<ISF32>(ea, e * ED + k);
            m0 = fmaf(a, we0[k], m0);
            m1 = fmaf(a, we1[k], m1);
        }
        acc0 += fmaxf(m0, 0.f);
        acc1 += fmaxf(m1, 0.f);
    }
    r0[threadIdx.x] = acc0; r1[threadIdx.x] = acc1;
    __syncthreads();
    if (threadIdx.x < 64) {
        const int l = threadIdx.x;
        float s0 = r0[l] + r0[l + 64] + r0[l + 128] + r0[l + 192];
        float s1 = r1[l] + r1[l + 64] + r1[l + 128] + r1[l + 192];
        part[2 * l]     = s0;   // plain store: block-private row
        part[2 * l + 1] = s1;
    }
}

// ---- component sums of x over nodes; block partial -> plain store ----
template<int FIN, bool ISF32>
__device__ __forceinline__ void mean_body(
    const void* __restrict__ x, float* __restrict__ part, int N,
    int relb, int nblk, float* lds)
{
    const int stride = nblk * 256;
    float acc[FIN];
#pragma unroll
    for (int k = 0; k < FIN; ++k) acc[k] = 0.f;
    for (int n = relb * 256 + threadIdx.x; n < N; n += stride) {
        if constexpr (FIN == 4) {
            const float4 xv = ld4<ISF32>(x, n);
            acc[0] += xv.x; acc[1] += xv.y; acc[2] += xv.z; acc[3] += xv.w;
        } else {
#pragma unroll
            for (int k = 0; k < FIN; ++k) acc[k] += ldf<ISF32>(x, n * FIN + k);
        }
    }
#pragma unroll
    for (int k = 0; k < FIN; ++k) acc[k] = wred(acc[k]);
    if ((threadIdx.x & 63) == 0) {
        const int w = threadIdx.x >> 6;
#pragma unroll
        for (int k = 0; k < 4; ++k) lds[w * 4 + k] = (k < FIN) ? acc[k] : 0.f;
    }
    __syncthreads();
    if (threadIdx.x < 4)
        part[threadIdx.x] = lds[threadIdx.x] + lds[4 + threadIdx.x]
                          + lds[8 + threadIdx.x] + lds[12 + threadIdx.x];
}

// ---- K1: counts + gine partials + mean partials ----
template<bool ISF32>
__device__ __forceinline__ void k1_body(const Par p, char* smem) {
    const int b = blockIdx.x;
    if (b < B1_CM) {
        count_m_body(p.ei_tv + ET, p.cnt_m, b, (int*)smem);
    } else if (b < B1_CM + B1_CO) {
        count_o_body(p.ei_log + EL, p.cnt_o, b - B1_CM);
    } else if (b < B1_CM + B1_CO + B1_GA) {
        const int rb = b - (B1_CM + B1_CO);
        gine_body<3, 3, ISF32>(p.ei_a, p.ea_a, p.x_m, p.We_a, p.be_a, p.Wm, p.bm,
                               p.part_a + rb * H, EA, rb, B1_GA,
                               (float*)smem, (float*)(smem + 1024));
    } else if (b < B1_CM + B1_CO + B1_GA + B1_GC) {
        const int rb = b - (B1_CM + B1_CO + B1_GA);
        gine_body<1, 4, ISF32>(p.ei_c, p.ea_c, p.x_o, p.We_c, p.be_c, p.Wo, p.bo,
                               p.part_c + rb * H, EC, rb, B1_GC,
                               (float*)smem, (float*)(smem + 1024));
    } else {
        const int rb = b - (B1_CM + B1_CO + B1_GA + B1_GC);
        if (rb < 8) mean_body<3, ISF32>(p.x_m, p.part_mn + rb * 4, NM, rb, 8, (float*)smem);
        else        mean_body<4, ISF32>(p.x_o, p.part_mn + rb * 4, NO, rb - 8, 40, (float*)smem);
    }
}

__global__ __launch_bounds__(256) void k1_kernel(const Par p) {
    __shared__ __align__(16) char smem[20032];
    if (*p.flag) k1_body<true >(p, smem);
    else         k1_body<false>(p, smem);
}

// ---- SAGE edge reduction, int4-batched, block partial -> plain store ----
template<bool ISF32>
__device__ __forceinline__ void sage_body(
    const void* __restrict__ x, const int* __restrict__ src,
    const int* __restrict__ dst, const int* __restrict__ cnt,
    float* __restrict__ part, int E, int relb, int nblk, float* lds)
{
    const int tid = threadIdx.x;
    const int nv = E >> 2;              // E divisible by 4 for all four edge sets
    const int stride = nblk * 256;
    float a0 = 0.f, a1 = 0.f, a2 = 0.f, a3 = 0.f, aw = 0.f;
    for (int i = relb * 256 + tid; i < nv; i += stride) {
        const int4 s4 = ((const int4*)src)[i];
        const int4 d4 = ((const int4*)dst)[i];
        const int c0 = cnt[d4.x], c1 = cnt[d4.y], c2 = cnt[d4.z], c3 = cnt[d4.w];
        const float4 x0 = ld4<ISF32>(x, s4.x);
        const float4 x1 = ld4<ISF32>(x, s4.y);
        const float4 x2 = ld4<ISF32>(x, s4.z);
        const float4 x3 = ld4<ISF32>(x, s4.w);
        const float i0 = __builtin_amdgcn_rcpf((float)(c0 > 0 ? c0 : 1));
        const float i1 = __builtin_amdgcn_rcpf((float)(c1 > 0 ? c1 : 1));
        const float i2 = __builtin_amdgcn_rcpf((float)(c2 > 0 ? c2 : 1));
        const float i3 = __builtin_amdgcn_rcpf((float)(c3 > 0 ? c3 : 1));
        a0 = fmaf(i0, x0.x, a0); a1 = fmaf(i0, x0.y, a1); a2 = fmaf(i0, x0.z, a2); a3 = fmaf(i0, x0.w, a3); aw += i0;
        a0 = fmaf(i1, x1.x, a0); a1 = fmaf(i1, x1.y, a1); a2 = fmaf(i1, x1.z, a2); a3 = fmaf(i1, x1.w, a3); aw += i1;
        a0 = fmaf(i2, x2.x, a0); a1 = fmaf(i2, x2.y, a1); a2 = fmaf(i2, x2.z, a2); a3 = fmaf(i2, x2.w, a3); aw += i2;
        a0 = fmaf(i3, x3.x, a0); a1 = fmaf(i3, x3.y, a1); a2 = fmaf(i3, x3.z, a2); a3 = fmaf(i3, x3.w, a3); aw += i3;
    }
    a0 = wred(a0); a1 = wred(a1); a2 = wred(a2); a3 = wred(a3); aw = wred(aw);
    if ((tid & 63) == 0) {
        float* w5 = lds + (tid >> 6) * 5;
        w5[0] = a0; w5[1] = a1; w5[2] = a2; w5[3] = a3; w5[4] = aw;
    }
    __syncthreads();
    if (tid < 5)
        part[tid] = lds[tid] + lds[5 + tid] + lds[10 + tid] + lds[15 + tid];
}

__global__ __launch_bounds__(256) void k2_kernel(const Par p) {
    __shared__ float lds[20];
    const bool f32 = (*p.flag) != 0;
    if (blockIdx.x < B2_TV) {
        const int rb = blockIdx.x;
        if (f32) sage_body<true >(p.x_o, p.ei_tv, p.ei_tv + ET, p.cnt_m, p.part_tv + rb * 8, ET, rb, B2_TV, lds);
        else     sage_body<false>(p.x_o, p.ei_tv, p.ei_tv + ET, p.cnt_m, p.part_tv + rb * 8, ET, rb, B2_TV, lds);
    } else {
        const int rb = blockIdx.x - B2_TV;
        if (f32) sage_body<true >(p.x_o, p.ei_log, p.ei_log + EL, p.cnt_o, p.part_lg + rb * 8, EL, rb, B2_LG, lds);
        else     sage_body<false>(p.x_o, p.ei_log, p.ei_log + EL, p.cnt_o, p.part_lg + rb * 8, EL, rb, B2_LG, lds);
    }
}

// ---- final: reduce partials, reconstruct means, five 128x128 mat-vecs ----
// scal: [0..3]=twx,[4]=tsw,[5..8]=lwx,[9]=lsw,[10..12]=xm,[13..16]=xo
template<bool ISF32>
__device__ __forceinline__ void final_body(const Par p) {
    __shared__ float scal[17];
    __shared__ float sha[H], shc[H];
    __shared__ float vtv[H], vmhm[H], va[H], vc[H], vlog[H], vmho[H];
    const int t = threadIdx.x;
    // phase A: scalar partial reductions (spread across waves)
    if (t < 5) {
        float s = 0.f;
        for (int r = 0; r < B2_TV; ++r) s += p.part_tv[r * 8 + t];
        scal[t] = s;
    } else if (t >= 64 && t < 69) {
        const int k = t - 64;
        float s = 0.f;
        for (int r = 0; r < B2_LG; ++r) s += p.part_lg[r * 8 + k];
        scal[5 + k] = s;
    } else if (t >= 128 && t < 131) {
        const int k = t - 128;
        float s = 0.f;
        for (int r = 0; r < 8; ++r) s += p.part_mn[r * 4 + k];
        scal[10 + k] = s;
    } else if (t >= 192 && t < 196) {
        const int k = t - 192;
        float s = 0.f;
        for (int r = 8; r < 48; ++r) s += p.part_mn[r * 4 + k];
        scal[13 + k] = s;
    }
    // phase B: channel partial reductions (coalesced)
    if (t < H) {
        float s = 0.f;
#pragma unroll 4
        for (int r = 0; r < B1_GA; ++r) s += p.part_a[r * H + t];
        sha[t] = s;
    } else {
        const int c = t - H;
        float s = 0.f;
#pragma unroll 4
        for (int r = 0; r < B1_GC; ++r) s += p.part_c[r * H + c];
        shc[c] = s;
    }
    __syncthreads();
    if (t < H) {
        float mhm = ldf<ISF32>(p.bm, t);
#pragma unroll
        for (int k = 0; k < 3; ++k)
            mhm = fmaf(scal[10 + k] * (1.f / NM), ldf<ISF32>(p.Wm, k * H + t), mhm);
        float mho = ldf<ISF32>(p.bo, t);
#pragma unroll
        for (int k = 0; k < 4; ++k)
            mho = fmaf(scal[13 + k] * (1.f / NO), ldf<ISF32>(p.Wo, k * H + t), mho);
        float tv = scal[4] * ldf<ISF32>(p.bo, t);
        float lg = scal[9] * ldf<ISF32>(p.bo, t);
#pragma unroll
        for (int k = 0; k < 4; ++k) {
            tv = fmaf(scal[k],     ldf<ISF32>(p.Wo, k * H + t), tv);
            lg = fmaf(scal[5 + k], ldf<ISF32>(p.Wo, k * H + t), lg);
        }
        vmhm[t] = mhm;
        vmho[t] = mho;
        vtv[t]  = tv * (1.f / NM);
        vlog[t] = lg * (1.f / NO);
        va[t] = sha[t] * (1.f / NO) + mho;
        vc[t] = shc[t] * (1.f / NO) + mho;
    }
    __syncthreads();
    float res; int oidx;
    if (t < H) {
        float acc = ldf<ISF32>(p.bl_tv, t);
        for (int k = 0; k < H; ++k) {
            acc = fmaf(vtv[k],  ldf<ISF32>(p.Wl_tv, k * H + t), acc);
            acc = fmaf(vmhm[k], ldf<ISF32>(p.Wr_tv, k * H + t), acc);
        }
        res = acc; oidx = t;
    } else {
        const int c = t - H;
        float acc = ldf<ISF32>(p.bn_a, c) + ldf<ISF32>(p.bn_c, c) + ldf<ISF32>(p.bl_log, c);
        for (int k = 0; k < H; ++k) {
            acc = fmaf(va[k],   ldf<ISF32>(p.Wn_a, k * H + c), acc);
            acc = fmaf(vc[k],   ldf<ISF32>(p.Wn_c, k * H + c), acc);
            acc = fmaf(vlog[k], ldf<ISF32>(p.Wl_log, k * H + c), acc);
            acc = fmaf(vmho[k], ldf<ISF32>(p.Wr_log, k * H + c), acc);
        }
        res = acc * (1.f / 3.f); oidx = H + c;
    }
    if constexpr (ISF32) ((float*)p.out)[oidx] = res;
    else                 ((bf16*)p.out)[oidx] = __float2bfloat16(res);
}

__global__ __launch_bounds__(256) void final_kernel(const Par p) {
    if (*p.flag) final_body<true >(p);
    else         final_body<false>(p);
}

extern "C" void kernel_launch(void* const* d_in, const int* in_sizes, int n_in,
                              void* d_out, int out_size, void* d_ws, size_t ws_size,
                              hipStream_t stream) {
    char* ws = (char*)d_ws;
    Par p;
    p.x_m   = d_in[0];  p.x_o   = d_in[1];
    p.ea_a  = d_in[2];  p.ea_c  = d_in[3];
    p.ei_a  = (const int*)d_in[4];
    p.ei_c  = (const int*)d_in[5];
    p.ei_tv = (const int*)d_in[6];
    p.ei_log= (const int*)d_in[7];
    p.Wm = d_in[8];  p.bm = d_in[9];  p.Wo = d_in[10]; p.bo = d_in[11];
    p.Wn_a = d_in[12]; p.bn_a = d_in[13]; p.We_a = d_in[14]; p.be_a = d_in[15];
    p.Wn_c = d_in[16]; p.bn_c = d_in[17]; p.We_c = d_in[18]; p.be_c = d_in[19];
    p.Wl_tv = d_in[20]; p.bl_tv = d_in[21]; p.Wr_tv = d_in[22];
    p.Wl_log = d_in[23]; p.bl_log = d_in[24]; p.Wr_log = d_in[25];

    // Workspace layout (bytes):
    //   [0,      20480)   cnt_m  int[NM] (padded)
    //   [20480,  421888)  cnt_o  int[NO] (padded)
    //   [421888, 421892)  flag   int
    //   [422144, 684288)  part_a  float[512][128]
    //   [684288, 815360)  part_c  float[256][128]
    //   [815360, 823552)  part_tv float[256][8]
    //   [823552, 831744)  part_lg float[256][8]
    //   [831744, 832512)  part_mn float[48][4]
    p.cnt_m   = (int*)(ws);
    p.cnt_o   = (int*)(ws + 20480);
    int* flag = (int*)(ws + 421888);
    p.part_a  = (float*)(ws + 422144);
    p.part_c  = (float*)(ws + 684288);
    p.part_tv = (float*)(ws + 815360);
    p.part_lg = (float*)(ws + 823552);
    p.part_mn = (float*)(ws + 831744);
    p.flag = flag;
    p.out  = d_out;

    // zero counts + flag: [0, 421892) -> 105473 ints (partials need no zeroing:
    // every slot is written unconditionally by its owning block)
    const int nzero = 105473;
    zero_kernel<<<(nzero + 255) / 256, 256, 0, stream>>>((int*)ws, nzero);

    // dtype probe on x_machine (first 15000 u16 — in-bounds under either dtype)
    detect_kernel<<<59, 256, 0, stream>>>((const uint16_t*)d_in[0], 15000, flag);

    k1_kernel<<<K1_BLOCKS, 256, 0, stream>>>(p);   // counts, gine_a/c, means
    k2_kernel<<<B2_TV + B2_LG, 256, 0, stream>>>(p); // sage_tv, sage_log
    final_kernel<<<1, 256, 0, stream>>>(p);
}

// Round 6
// 276.657 us; speedup vs baseline: 1.7598x; 1.2509x over previous
//
#include <hip/hip_runtime.h>
#include <hip/hip_bf16.h>
#include <stdint.h>

// Problem constants (from reference)
#define H   128
#define NM  5000
#define NO  100000
#define EA  1000000
#define EC  500000
#define ET  1000000
#define EL  500000

typedef __hip_bfloat16 bf16;

// K1 block partition: counts_m | counts_o | gine_a | gine_c | means
#define B1_CM 32
#define B1_CO 128
#define B1_GA 1024
#define B1_GC 512
#define B1_MN 48
#define K1_BLOCKS (B1_CM + B1_CO + B1_GA + B1_GC + B1_MN)
// K2 block partition: sage_tv | sage_log
#define B2_TV 256
#define B2_LG 256

struct Par {
    const void *x_m, *x_o, *ea_a, *ea_c;
    const int *ei_a, *ei_c, *ei_tv, *ei_log;
    const void *Wm, *bm, *Wo, *bo;
    const void *Wn_a, *bn_a, *We_a, *be_a;
    const void *Wn_c, *bn_c, *We_c, *be_c;
    const void *Wl_tv, *bl_tv, *Wr_tv, *Wl_log, *bl_log, *Wr_log;
    int *cnt_m, *cnt_o;
    float *part_a, *part_c, *part_tv, *part_lg, *part_mn;
    const int *flag;
    void *out;
};

// ---- dtype-flexible loads ----
template<bool ISF32>
__device__ __forceinline__ float ldf(const void* p, int i) {
    if constexpr (ISF32) return ((const float*)p)[i];
    else                 return __bfloat162float(((const bf16*)p)[i]);
}

__device__ __forceinline__ float bflo(uint32_t v) {
    union { uint32_t u; float f; } c; c.u = v << 16; return c.f;
}
__device__ __forceinline__ float bfhi(uint32_t v) {
    union { uint32_t u; float f; } c; c.u = v & 0xFFFF0000u; return c.f;
}

template<bool ISF32>
__device__ __forceinline__ float4 ld4(const void* p, int row) {
    if constexpr (ISF32) return ((const float4*)p)[row];
    else {
        const uint2 t = ((const uint2*)p)[row];
        float4 r; r.x = bflo(t.x); r.y = bfhi(t.x); r.z = bflo(t.y); r.w = bfhi(t.y);
        return r;
    }
}

__device__ __forceinline__ float wred(float v) {
#pragma unroll
    for (int o = 32; o; o >>= 1) v += __shfl_down(v, o, 64);
    return v;
}

// ---- zero scratch ----
__global__ void zero_kernel(int* __restrict__ p, int n) {
    int i = blockIdx.x * blockDim.x + threadIdx.x;
    if (i < n) p[i] = 0;
}

// ---- dtype probe ----
__global__ void detect_kernel(const uint16_t* __restrict__ x, int n, int* __restrict__ flag) {
    int i = blockIdx.x * blockDim.x + threadIdx.x;
    if (i < n) {
        if (((x[i] >> 7) & 0xFF) == 0xFF) atomicOr(flag, 1);
    }
}

// ---- counts ----
__device__ __forceinline__ void count_m_body(
    const int* __restrict__ dst, int* __restrict__ cnt, int relb, int* hist)
{
    for (int i = threadIdx.x; i < NM; i += 256) hist[i] = 0;
    __syncthreads();
    const int chunk = (ET + B1_CM - 1) / B1_CM;
    const int e0 = relb * chunk;
    int e1 = e0 + chunk; if (e1 > ET) e1 = ET;
    for (int i = e0 + threadIdx.x; i < e1; i += 256)
        atomicAdd(&hist[dst[i]], 1);
    __syncthreads();
    for (int i = threadIdx.x; i < NM; i += 256) {
        const int v = hist[i];
        if (v) atomicAdd(&cnt[i], v);
    }
}

__device__ __forceinline__ void count_o_body(
    const int* __restrict__ dst, int* __restrict__ cnt, int relb)
{
    const int stride = B1_CO * 256;
    for (int i = relb * 256 + threadIdx.x; i < EL; i += stride)
        atomicAdd(&cnt[dst[i]], 1);
}

// ---- GINE edge sum, 4-edge batched; block partial -> plain store ----
template<int ED, int FIN, bool ISF32>
__device__ __forceinline__ void gine_body(
    const int* __restrict__ src, const void* __restrict__ ea,
    const void* __restrict__ x, const void* __restrict__ We,
    const void* __restrict__ be, const void* __restrict__ Wx,
    const void* __restrict__ bx, float* __restrict__ part,
    int E, int relb, int nblk, float* r0, float* r1)
{
    const int lane = threadIdx.x & 63;
    const int c0 = 2 * lane, c1 = c0 + 1;
    float we0[ED], we1[ED], wx0[FIN], wx1[FIN];
#pragma unroll
    for (int k = 0; k < ED; ++k) {
        we0[k] = ldf<ISF32>(We, k * H + c0);
        we1[k] = ldf<ISF32>(We, k * H + c1);
    }
#pragma unroll
    for (int k = 0; k < FIN; ++k) {
        wx0[k] = ldf<ISF32>(Wx, k * H + c0);
        wx1[k] = ldf<ISF32>(Wx, k * H + c1);
    }
    const float b0 = ldf<ISF32>(be, c0) + ldf<ISF32>(bx, c0);
    const float b1 = ldf<ISF32>(be, c1) + ldf<ISF32>(bx, c1);

    const int wv = relb * 4 + (threadIdx.x >> 6);
    const int nw = nblk * 4;
    const int chunk = (((E + nw - 1) / nw) + 3) & ~3;   // multiple of 4
    int e0 = wv * chunk;
    int e1 = e0 + chunk; if (e1 > E) e1 = E; if (e0 > E) e0 = E;

    float acc0 = 0.f, acc1 = 0.f;
    for (int e = e0; e < e1; e += 4) {
        const int4 s4 = *(const int4*)(src + e);
        // edge attrs for 4 edges (vectorized fp32 paths)
        float A[4][ED];
        if constexpr (ISF32 && ED == 3) {
            const float4* q = (const float4*)((const float*)ea + e * 3);
            const float4 q0 = q[0], q1 = q[1], q2 = q[2];
            A[0][0]=q0.x; A[0][1]=q0.y; A[0][2]=q0.z;
            A[1][0]=q0.w; A[1][1]=q1.x; A[1][2]=q1.y;
            A[2][0]=q1.z; A[2][1]=q1.w; A[2][2]=q2.x;
            A[3][0]=q2.y; A[3][1]=q2.z; A[3][2]=q2.w;
        } else if constexpr (ISF32 && ED == 1) {
            const float4 q = *(const float4*)((const float*)ea + e);
            A[0][0]=q.x; A[1][0]=q.y; A[2][0]=q.z; A[3][0]=q.w;
        } else {
#pragma unroll
            for (int j = 0; j < 4; ++j)
#pragma unroll
                for (int k = 0; k < ED; ++k)
                    A[j][k] = ldf<ISF32>(ea, (e + j) * ED + k);
        }
        // x rows for 4 srcs (independent gathers, all in flight)
        const int ss[4] = {s4.x, s4.y, s4.z, s4.w};
        float X[4][FIN];
#pragma unroll
        for (int j = 0; j < 4; ++j) {
            if constexpr (FIN == 4) {
                const float4 xv = ld4<ISF32>(x, ss[j]);
                X[j][0]=xv.x; X[j][1]=xv.y; X[j][2]=xv.z; X[j][3]=xv.w;
            } else {
#pragma unroll
                for (int k = 0; k < FIN; ++k)
                    X[j][k] = ldf<ISF32>(x, ss[j] * FIN + k);
            }
        }
#pragma unroll
        for (int j = 0; j < 4; ++j) {
            float m0 = b0, m1 = b1;
#pragma unroll
            for (int k = 0; k < FIN; ++k) {
                m0 = fmaf(X[j][k], wx0[k], m0);
                m1 = fmaf(X[j][k], wx1[k], m1);
            }
#pragma unroll
            for (int k = 0; k < ED; ++k) {
                m0 = fmaf(A[j][k], we0[k], m0);
                m1 = fmaf(A[j][k], we1[k], m1);
            }
            acc0 += fmaxf(m0, 0.f);
            acc1 += fmaxf(m1, 0.f);
        }
    }
    r0[threadIdx.x] = acc0; r1[threadIdx.x] = acc1;
    __syncthreads();
    if (threadIdx.x < 64) {
        const int l = threadIdx.x;
        float s0 = r0[l] + r0[l + 64] + r0[l + 128] + r0[l + 192];
        float s1 = r1[l] + r1[l + 64] + r1[l + 128] + r1[l + 192];
        part[2 * l]     = s0;
        part[2 * l + 1] = s1;
    }
}

// ---- component sums of x over nodes ----
template<int FIN, bool ISF32>
__device__ __forceinline__ void mean_body(
    const void* __restrict__ x, float* __restrict__ part, int N,
    int relb, int nblk, float* lds)
{
    const int stride = nblk * 256;
    float acc[FIN];
#pragma unroll
    for (int k = 0; k < FIN; ++k) acc[k] = 0.f;
    for (int n = relb * 256 + threadIdx.x; n < N; n += stride) {
        if constexpr (FIN == 4) {
            const float4 xv = ld4<ISF32>(x, n);
            acc[0] += xv.x; acc[1] += xv.y; acc[2] += xv.z; acc[3] += xv.w;
        } else {
#pragma unroll
            for (int k = 0; k < FIN; ++k) acc[k] += ldf<ISF32>(x, n * FIN + k);
        }
    }
#pragma unroll
    for (int k = 0; k < FIN; ++k) acc[k] = wred(acc[k]);
    if ((threadIdx.x & 63) == 0) {
        const int w = threadIdx.x >> 6;
#pragma unroll
        for (int k = 0; k < 4; ++k) lds[w * 4 + k] = (k < FIN) ? acc[k] : 0.f;
    }
    __syncthreads();
    if (threadIdx.x < 4)
        part[threadIdx.x] = lds[threadIdx.x] + lds[4 + threadIdx.x]
                          + lds[8 + threadIdx.x] + lds[12 + threadIdx.x];
}

// ---- K1 ----
template<bool ISF32>
__device__ __forceinline__ void k1_body(const Par p, char* smem) {
    const int b = blockIdx.x;
    if (b < B1_CM) {
        count_m_body(p.ei_tv + ET, p.cnt_m, b, (int*)smem);
    } else if (b < B1_CM + B1_CO) {
        count_o_body(p.ei_log + EL, p.cnt_o, b - B1_CM);
    } else if (b < B1_CM + B1_CO + B1_GA) {
        const int rb = b - (B1_CM + B1_CO);
        gine_body<3, 3, ISF32>(p.ei_a, p.ea_a, p.x_m, p.We_a, p.be_a, p.Wm, p.bm,
                               p.part_a + rb * H, EA, rb, B1_GA,
                               (float*)smem, (float*)(smem + 1024));
    } else if (b < B1_CM + B1_CO + B1_GA + B1_GC) {
        const int rb = b - (B1_CM + B1_CO + B1_GA);
        gine_body<1, 4, ISF32>(p.ei_c, p.ea_c, p.x_o, p.We_c, p.be_c, p.Wo, p.bo,
                               p.part_c + rb * H, EC, rb, B1_GC,
                               (float*)smem, (float*)(smem + 1024));
    } else {
        const int rb = b - (B1_CM + B1_CO + B1_GA + B1_GC);
        if (rb < 8) mean_body<3, ISF32>(p.x_m, p.part_mn + rb * 4, NM, rb, 8, (float*)smem);
        else        mean_body<4, ISF32>(p.x_o, p.part_mn + rb * 4, NO, rb - 8, 40, (float*)smem);
    }
}

__global__ __launch_bounds__(256) void k1_kernel(const Par p) {
    __shared__ __align__(16) char smem[20032];
    if (*p.flag) k1_body<true >(p, smem);
    else         k1_body<false>(p, smem);
}

// ---- SAGE edge reduction, int4-batched ----
template<bool ISF32>
__device__ __forceinline__ void sage_body(
    const void* __restrict__ x, const int* __restrict__ src,
    const int* __restrict__ dst, const int* __restrict__ cnt,
    float* __restrict__ part, int E, int relb, int nblk, float* lds)
{
    const int tid = threadIdx.x;
    const int nv = E >> 2;
    const int stride = nblk * 256;
    float a0 = 0.f, a1 = 0.f, a2 = 0.f, a3 = 0.f, aw = 0.f;
#pragma unroll 2
    for (int i = relb * 256 + tid; i < nv; i += stride) {
        const int4 s4 = ((const int4*)src)[i];
        const int4 d4 = ((const int4*)dst)[i];
        const int c0 = cnt[d4.x], c1 = cnt[d4.y], c2 = cnt[d4.z], c3 = cnt[d4.w];
        const float4 x0 = ld4<ISF32>(x, s4.x);
        const float4 x1 = ld4<ISF32>(x, s4.y);
        const float4 x2 = ld4<ISF32>(x, s4.z);
        const float4 x3 = ld4<ISF32>(x, s4.w);
        const float i0 = __builtin_amdgcn_rcpf((float)(c0 > 0 ? c0 : 1));
        const float i1 = __builtin_amdgcn_rcpf((float)(c1 > 0 ? c1 : 1));
        const float i2 = __builtin_amdgcn_rcpf((float)(c2 > 0 ? c2 : 1));
        const float i3 = __builtin_amdgcn_rcpf((float)(c3 > 0 ? c3 : 1));
        a0 = fmaf(i0, x0.x, a0); a1 = fmaf(i0, x0.y, a1); a2 = fmaf(i0, x0.z, a2); a3 = fmaf(i0, x0.w, a3); aw += i0;
        a0 = fmaf(i1, x1.x, a0); a1 = fmaf(i1, x1.y, a1); a2 = fmaf(i1, x1.z, a2); a3 = fmaf(i1, x1.w, a3); aw += i1;
        a0 = fmaf(i2, x2.x, a0); a1 = fmaf(i2, x2.y, a1); a2 = fmaf(i2, x2.z, a2); a3 = fmaf(i2, x2.w, a3); aw += i2;
        a0 = fmaf(i3, x3.x, a0); a1 = fmaf(i3, x3.y, a1); a2 = fmaf(i3, x3.z, a2); a3 = fmaf(i3, x3.w, a3); aw += i3;
    }
    a0 = wred(a0); a1 = wred(a1); a2 = wred(a2); a3 = wred(a3); aw = wred(aw);
    if ((tid & 63) == 0) {
        float* w5 = lds + (tid >> 6) * 5;
        w5[0] = a0; w5[1] = a1; w5[2] = a2; w5[3] = a3; w5[4] = aw;
    }
    __syncthreads();
    if (tid < 5)
        part[tid] = lds[tid] + lds[5 + tid] + lds[10 + tid] + lds[15 + tid];
}

__global__ __launch_bounds__(256) void k2_kernel(const Par p) {
    __shared__ int scnt[NM];          // 20 KB: LDS-staged cnt_m for tv branch
    __shared__ float lds[20];
    const bool f32 = (*p.flag) != 0;
    if (blockIdx.x < B2_TV) {
        for (int i = threadIdx.x; i < NM; i += 256) scnt[i] = p.cnt_m[i];
        __syncthreads();
        const int rb = blockIdx.x;
        if (f32) sage_body<true >(p.x_o, p.ei_tv, p.ei_tv + ET, scnt, p.part_tv + rb * 8, ET, rb, B2_TV, lds);
        else     sage_body<false>(p.x_o, p.ei_tv, p.ei_tv + ET, scnt, p.part_tv + rb * 8, ET, rb, B2_TV, lds);
    } else {
        const int rb = blockIdx.x - B2_TV;
        if (f32) sage_body<true >(p.x_o, p.ei_log, p.ei_log + EL, p.cnt_o, p.part_lg + rb * 8, EL, rb, B2_LG, lds);
        else     sage_body<false>(p.x_o, p.ei_log, p.ei_log + EL, p.cnt_o, p.part_lg + rb * 8, EL, rb, B2_LG, lds);
    }
}

// ---- final ----
// scal: [0..3]=twx,[4]=tsw,[5..8]=lwx,[9]=lsw,[10..12]=xm,[13..16]=xo
template<bool ISF32>
__device__ __forceinline__ void final_body(const Par p) {
    __shared__ float scal[17];
    __shared__ float segtv[5][8], seglg[5][8];
    __shared__ float sh2a[2][H], sh2c[2][H];
    __shared__ float sha[H], shc[H];
    __shared__ float vtv[H], vmhm[H], va[H], vc[H], vlog[H], vmho[H];
    const int t = threadIdx.x;

    // phase B: column halves (all 256 threads)
    {
        const int col = t & 127, half = t >> 7;
        float sA = 0.f;
        const float* pa = p.part_a + (half * (B1_GA / 2)) * H + col;
#pragma unroll 8
        for (int r = 0; r < B1_GA / 2; ++r) sA += pa[r * H];
        sh2a[half][col] = sA;
        float sC = 0.f;
        const float* pc = p.part_c + (half * (B1_GC / 2)) * H + col;
#pragma unroll 8
        for (int r = 0; r < B1_GC / 2; ++r) sC += pc[r * H];
        sh2c[half][col] = sC;
    }
    // phase A: scalar partials, segmented
    if (t < 40) {
        const int k = t >> 3, seg = t & 7;
        float s = 0.f;
        const int r0 = seg * (B2_TV / 8);
#pragma unroll 4
        for (int r = r0; r < r0 + B2_TV / 8; ++r) s += p.part_tv[r * 8 + k];
        segtv[k][seg] = s;
    } else if (t >= 64 && t < 104) {
        const int k = (t - 64) >> 3, seg = (t - 64) & 7;
        float s = 0.f;
        const int r0 = seg * (B2_LG / 8);
#pragma unroll 4
        for (int r = r0; r < r0 + B2_LG / 8; ++r) s += p.part_lg[r * 8 + k];
        seglg[k][seg] = s;
    } else if (t >= 128 && t < 131) {
        const int k = t - 128;
        float s = 0.f;
        for (int r = 0; r < 8; ++r) s += p.part_mn[r * 4 + k];
        scal[10 + k] = s;
    } else if (t >= 192 && t < 196) {
        const int k = t - 192;
        float s = 0.f;
#pragma unroll 4
        for (int r = 8; r < 48; ++r) s += p.part_mn[r * 4 + k];
        scal[13 + k] = s;
    }
    __syncthreads();
    if (t < 5) {
        float s = 0.f;
#pragma unroll
        for (int g = 0; g < 8; ++g) s += segtv[t][g];
        scal[t] = s;
    } else if (t >= 64 && t < 69) {
        const int k = t - 64;
        float s = 0.f;
#pragma unroll
        for (int g = 0; g < 8; ++g) s += seglg[k][g];
        scal[5 + k] = s;
    }
    if (t < H) sha[t] = sh2a[0][t] + sh2a[1][t];
    else       shc[t - H] = sh2c[0][t - H] + sh2c[1][t - H];
    __syncthreads();

    if (t < H) {
        float mhm = ldf<ISF32>(p.bm, t);
#pragma unroll
        for (int k = 0; k < 3; ++k)
            mhm = fmaf(scal[10 + k] * (1.f / NM), ldf<ISF32>(p.Wm, k * H + t), mhm);
        float mho = ldf<ISF32>(p.bo, t);
#pragma unroll
        for (int k = 0; k < 4; ++k)
            mho = fmaf(scal[13 + k] * (1.f / NO), ldf<ISF32>(p.Wo, k * H + t), mho);
        float tv = scal[4] * ldf<ISF32>(p.bo, t);
        float lg = scal[9] * ldf<ISF32>(p.bo, t);
#pragma unroll
        for (int k = 0; k < 4; ++k) {
            tv = fmaf(scal[k],     ldf<ISF32>(p.Wo, k * H + t), tv);
            lg = fmaf(scal[5 + k], ldf<ISF32>(p.Wo, k * H + t), lg);
        }
        vmhm[t] = mhm;
        vmho[t] = mho;
        vtv[t]  = tv * (1.f / NM);
        vlog[t] = lg * (1.f / NO);
        va[t] = sha[t] * (1.f / NO) + mho;
        vc[t] = shc[t] * (1.f / NO) + mho;
    }
    __syncthreads();
    float res; int oidx;
    if (t < H) {
        float acc = ldf<ISF32>(p.bl_tv, t);
        for (int k = 0; k < H; ++k) {
            acc = fmaf(vtv[k],  ldf<ISF32>(p.Wl_tv, k * H + t), acc);
            acc = fmaf(vmhm[k], ldf<ISF32>(p.Wr_tv, k * H + t), acc);
        }
        res = acc; oidx = t;
    } else {
        const int c = t - H;
        float acc = ldf<ISF32>(p.bn_a, c) + ldf<ISF32>(p.bn_c, c) + ldf<ISF32>(p.bl_log, c);
        for (int k = 0; k < H; ++k) {
            acc = fmaf(va[k],   ldf<ISF32>(p.Wn_a, k * H + c), acc);
            acc = fmaf(vc[k],   ldf<ISF32>(p.Wn_c, k * H + c), acc);
            acc = fmaf(vlog[k], ldf<ISF32>(p.Wl_log, k * H + c), acc);
            acc = fmaf(vmho[k], ldf<ISF32>(p.Wr_log, k * H + c), acc);
        }
        res = acc * (1.f / 3.f); oidx = H + c;
    }
    if constexpr (ISF32) ((float*)p.out)[oidx] = res;
    else                 ((bf16*)p.out)[oidx] = __float2bfloat16(res);
}

__global__ __launch_bounds__(256) void final_kernel(const Par p) {
    if (*p.flag) final_body<true >(p);
    else         final_body<false>(p);
}

extern "C" void kernel_launch(void* const* d_in, const int* in_sizes, int n_in,
                              void* d_out, int out_size, void* d_ws, size_t ws_size,
                              hipStream_t stream) {
    char* ws = (char*)d_ws;
    Par p;
    p.x_m   = d_in[0];  p.x_o   = d_in[1];
    p.ea_a  = d_in[2];  p.ea_c  = d_in[3];
    p.ei_a  = (const int*)d_in[4];
    p.ei_c  = (const int*)d_in[5];
    p.ei_tv = (const int*)d_in[6];
    p.ei_log= (const int*)d_in[7];
    p.Wm = d_in[8];  p.bm = d_in[9];  p.Wo = d_in[10]; p.bo = d_in[11];
    p.Wn_a = d_in[12]; p.bn_a = d_in[13]; p.We_a = d_in[14]; p.be_a = d_in[15];
    p.Wn_c = d_in[16]; p.bn_c = d_in[17]; p.We_c = d_in[18]; p.be_c = d_in[19];
    p.Wl_tv = d_in[20]; p.bl_tv = d_in[21]; p.Wr_tv = d_in[22];
    p.Wl_log = d_in[23]; p.bl_log = d_in[24]; p.Wr_log = d_in[25];

    // Workspace layout (bytes):
    //   [0,       20480)    cnt_m  int[NM] (padded)
    //   [20480,   421888)   cnt_o  int[NO] (padded)
    //   [421888,  421892)   flag   int
    //   [422144,  946432)   part_a  float[1024][128]
    //   [946432,  1208576)  part_c  float[512][128]
    //   [1208576, 1216768)  part_tv float[256][8]
    //   [1216768, 1224960)  part_lg float[256][8]
    //   [1224960, 1225728)  part_mn float[48][4]
    p.cnt_m   = (int*)(ws);
    p.cnt_o   = (int*)(ws + 20480);
    int* flag = (int*)(ws + 421888);
    p.part_a  = (float*)(ws + 422144);
    p.part_c  = (float*)(ws + 946432);
    p.part_tv = (float*)(ws + 1208576);
    p.part_lg = (float*)(ws + 1216768);
    p.part_mn = (float*)(ws + 1224960);
    p.flag = flag;
    p.out  = d_out;

    // zero counts + flag: [0, 421892) -> 105473 ints
    const int nzero = 105473;
    zero_kernel<<<(nzero + 255) / 256, 256, 0, stream>>>((int*)ws, nzero);

    detect_kernel<<<59, 256, 0, stream>>>((const uint16_t*)d_in[0], 15000, flag);

    k1_kernel<<<K1_BLOCKS, 256, 0, stream>>>(p);     // counts, gine_a/c, means
    k2_kernel<<<B2_TV + B2_LG, 256, 0, stream>>>(p); // sage_tv, sage_log
    final_kernel<<<1, 256, 0, stream>>>(p);
}

// Round 7
// 243.735 us; speedup vs baseline: 1.9975x; 1.1351x over previous
//
#include <hip/hip_runtime.h>
#include <hip/hip_bf16.h>
#include <stdint.h>

// Problem constants (from reference)
#define H   128
#define NM  5000
#define NO  100000
#define EA  1000000
#define EC  500000
#define ET  1000000
#define EL  500000

typedef __hip_bfloat16 bf16;
typedef float v2f __attribute__((ext_vector_type(2)));

// main kernel partition: gine_a | gine_c | sage_tv | sage_log | means
#define B_GA 512
#define B_GC 256
#define B_TV 512
#define B_LG 256
#define B_MN 48
#define MAIN_BLOCKS (B_GA + B_GC + B_TV + B_LG + B_MN)
// aux kernel partition: detect | cnt_m hist | cnt_o spread
#define A_DET 59
#define A_CM  32
#define A_CO  192
#define AUX_BLOCKS (A_DET + A_CM + A_CO)

struct Par {
    const void *x_m, *x_o, *ea_a, *ea_c;
    const int *ei_a, *ei_c, *ei_tv, *ei_log;
    const void *Wm, *bm, *Wo, *bo;
    const void *Wn_a, *bn_a, *We_a, *be_a;
    const void *Wn_c, *bn_c, *We_c, *be_c;
    const void *Wl_tv, *bl_tv, *Wr_tv, *Wl_log, *bl_log, *Wr_log;
    int *cnt_m, *cnt_o;
    float *part_a, *part_c, *part_tv, *part_lg, *part_mn;
    const int *flag;
    int *flagw;
    void *out;
};

// ---- dtype-flexible loads ----
template<bool ISF32>
__device__ __forceinline__ float ldf(const void* p, int i) {
    if constexpr (ISF32) return ((const float*)p)[i];
    else                 return __bfloat162float(((const bf16*)p)[i]);
}

__device__ __forceinline__ float bflo(uint32_t v) {
    union { uint32_t u; float f; } c; c.u = v << 16; return c.f;
}
__device__ __forceinline__ float bfhi(uint32_t v) {
    union { uint32_t u; float f; } c; c.u = v & 0xFFFF0000u; return c.f;
}

template<bool ISF32>
__device__ __forceinline__ float4 ld4(const void* p, int row) {
    if constexpr (ISF32) return ((const float4*)p)[row];
    else {
        const uint2 t = ((const uint2*)p)[row];
        float4 r; r.x = bflo(t.x); r.y = bfhi(t.x); r.z = bflo(t.y); r.w = bfhi(t.y);
        return r;
    }
}

__device__ __forceinline__ float wred(float v) {
#pragma unroll
    for (int o = 32; o; o >>= 1) v += __shfl_down(v, o, 64);
    return v;
}

// ---- zero scratch ----
__global__ void zero_kernel(int* __restrict__ p, int n) {
    int i = blockIdx.x * blockDim.x + threadIdx.x;
    if (i < n) p[i] = 0;
}

// ---- aux: detect | cnt_m LDS hist | cnt_o spread atomics ----
__device__ __forceinline__ void count_m_body(
    const int* __restrict__ dst, int* __restrict__ cnt, int relb, int* hist)
{
    for (int i = threadIdx.x; i < NM; i += 256) hist[i] = 0;
    __syncthreads();
    const int chunk = (ET + A_CM - 1) / A_CM;
    const int e0 = relb * chunk;
    int e1 = e0 + chunk; if (e1 > ET) e1 = ET;
    for (int i = e0 + threadIdx.x; i < e1; i += 256)
        atomicAdd(&hist[dst[i]], 1);
    __syncthreads();
    for (int i = threadIdx.x; i < NM; i += 256) {
        const int v = hist[i];
        if (v) atomicAdd(&cnt[i], v);
    }
}

__global__ __launch_bounds__(256) void aux_kernel(const Par p) {
    __shared__ int hist[NM];
    const int b = blockIdx.x;
    if (b < A_DET) {
        const int i = b * 256 + threadIdx.x;
        if (i < 15000) {
            const uint16_t v = ((const uint16_t*)p.x_m)[i];
            if (((v >> 7) & 0xFF) == 0xFF) atomicOr(p.flagw, 1);
        }
    } else if (b < A_DET + A_CM) {
        count_m_body(p.ei_tv + ET, p.cnt_m, b - A_DET, hist);
    } else {
        const int relb = b - (A_DET + A_CM);
        const int* __restrict__ dst = p.ei_log + EL;
        const int stride = A_CO * 256;
        for (int i = relb * 256 + threadIdx.x; i < EL; i += stride)
            atomicAdd(&p.cnt_o[dst[i]], 1);
    }
}

// ---- GINE: coalesced stage -> LDS broadcast -> pk-fma channel math ----
// Per wave: granules of 64 edges. Stage: lane j loads edge j's features
// (coalesced/gathered), 2x ds_write_b128 into wave-private LDS slot.
// Compute: loop 64 edges, 2x ds_read_b128 broadcast + KT pk-FMAs.
template<int FIN, int ED, bool ISF32>
__device__ __forceinline__ void gine_body(
    const int* __restrict__ src, const void* __restrict__ ea,
    const void* __restrict__ x, const void* __restrict__ We,
    const void* __restrict__ be, const void* __restrict__ Wx,
    const void* __restrict__ bx, float* __restrict__ part,
    int E, int relb, int nblk, float* stage, float* r0, float* r1)
{
    constexpr int KT = FIN + ED;
    const int lane = threadIdx.x & 63;
    const int wv = threadIdx.x >> 6;
    const int c0 = 2 * lane;
    v2f wc[KT];
#pragma unroll
    for (int k = 0; k < FIN; ++k)
        wc[k] = (v2f){ldf<ISF32>(Wx, k * H + c0), ldf<ISF32>(Wx, k * H + c0 + 1)};
#pragma unroll
    for (int k = 0; k < ED; ++k)
        wc[FIN + k] = (v2f){ldf<ISF32>(We, k * H + c0), ldf<ISF32>(We, k * H + c0 + 1)};
    const v2f bb = (v2f){ldf<ISF32>(bx, c0) + ldf<ISF32>(be, c0),
                         ldf<ISF32>(bx, c0 + 1) + ldf<ISF32>(be, c0 + 1)};

    float* myst = stage + wv * 512;              // 64 edges x 8 floats
    float4* st4 = (float4*)(myst + lane * 8);
    const float4* rd4 = (const float4*)myst;

    v2f acc = (v2f){0.f, 0.f};
    const int G = (E + 63) >> 6;
    const int NW = nblk * 4;
    for (int g = relb * 4 + wv; g < G; g += NW) {
        const int base = g << 6;
        const int ecnt = min(64, E - base);
        const int ej = base + (lane < ecnt ? lane : ecnt - 1);
        float f[8];
#pragma unroll
        for (int k = 0; k < 8; ++k) f[k] = 0.f;
        const int s = src[ej];
        if constexpr (FIN == 4) {
            const float4 xv = ld4<ISF32>(x, s);
            f[0] = xv.x; f[1] = xv.y; f[2] = xv.z; f[3] = xv.w;
        } else {
#pragma unroll
            for (int k = 0; k < FIN; ++k) f[k] = ldf<ISF32>(x, s * FIN + k);
        }
#pragma unroll
        for (int k = 0; k < ED; ++k) f[FIN + k] = ldf<ISF32>(ea, ej * ED + k);
        st4[0] = (float4){f[0], f[1], f[2], f[3]};
        st4[1] = (float4){f[4], f[5], f[6], f[7]};
        // broadcast-compute over staged edges (compiler inserts lgkmcnt wait)
#pragma unroll 2
        for (int jj = 0; jj < ecnt; ++jj) {
            float fe[8];
            {
                const float4 lo = rd4[jj * 2];
                fe[0] = lo.x; fe[1] = lo.y; fe[2] = lo.z; fe[3] = lo.w;
            }
            if constexpr (KT > 4) {
                const float4 hi = rd4[jj * 2 + 1];
                fe[4] = hi.x; fe[5] = hi.y; fe[6] = hi.z; fe[7] = hi.w;
            }
            v2f m = bb;
#pragma unroll
            for (int k = 0; k < KT; ++k)
                m += wc[k] * (v2f){fe[k], fe[k]};
            m.x = fmaxf(m.x, 0.f);
            m.y = fmaxf(m.y, 0.f);
            acc += m;
        }
    }
    r0[threadIdx.x] = acc.x; r1[threadIdx.x] = acc.y;
    __syncthreads();
    if (threadIdx.x < 64) {
        const int l = threadIdx.x;
        float s0 = r0[l] + r0[l + 64] + r0[l + 128] + r0[l + 192];
        float s1 = r1[l] + r1[l + 64] + r1[l + 128] + r1[l + 192];
        part[2 * l]     = s0;
        part[2 * l + 1] = s1;
    }
}

// ---- component sums of x over nodes ----
template<int FIN, bool ISF32>
__device__ __forceinline__ void mean_body(
    const void* __restrict__ x, float* __restrict__ part, int N,
    int relb, int nblk, float* lds)
{
    const int stride = nblk * 256;
    float acc[FIN];
#pragma unroll
    for (int k = 0; k < FIN; ++k) acc[k] = 0.f;
    for (int n = relb * 256 + threadIdx.x; n < N; n += stride) {
        if constexpr (FIN == 4) {
            const float4 xv = ld4<ISF32>(x, n);
            acc[0] += xv.x; acc[1] += xv.y; acc[2] += xv.z; acc[3] += xv.w;
        } else {
#pragma unroll
            for (int k = 0; k < FIN; ++k) acc[k] += ldf<ISF32>(x, n * FIN + k);
        }
    }
#pragma unroll
    for (int k = 0; k < FIN; ++k) acc[k] = wred(acc[k]);
    if ((threadIdx.x & 63) == 0) {
        const int w = threadIdx.x >> 6;
#pragma unroll
        for (int k = 0; k < 4; ++k) lds[w * 4 + k] = (k < FIN) ? acc[k] : 0.f;
    }
    __syncthreads();
    if (threadIdx.x < 4)
        part[threadIdx.x] = lds[threadIdx.x] + lds[4 + threadIdx.x]
                          + lds[8 + threadIdx.x] + lds[12 + threadIdx.x];
}

// ---- SAGE edge reduction, int4-batched; cnt gathered via L1/L2 ----
template<bool ISF32>
__device__ __forceinline__ void sage_body(
    const void* __restrict__ x, const int* __restrict__ src,
    const int* __restrict__ dst, const int* __restrict__ cnt,
    float* __restrict__ part, int E, int relb, int nblk, float* lds)
{
    const int tid = threadIdx.x;
    const int nv = E >> 2;
    const int stride = nblk * 256;
    float a0 = 0.f, a1 = 0.f, a2 = 0.f, a3 = 0.f, aw = 0.f;
#pragma unroll 2
    for (int i = relb * 256 + tid; i < nv; i += stride) {
        const int4 s4 = ((const int4*)src)[i];
        const int4 d4 = ((const int4*)dst)[i];
        const int c0 = cnt[d4.x], c1 = cnt[d4.y], c2 = cnt[d4.z], c3 = cnt[d4.w];
        const float4 x0 = ld4<ISF32>(x, s4.x);
        const float4 x1 = ld4<ISF32>(x, s4.y);
        const float4 x2 = ld4<ISF32>(x, s4.z);
        const float4 x3 = ld4<ISF32>(x, s4.w);
        const float i0 = __builtin_amdgcn_rcpf((float)(c0 > 0 ? c0 : 1));
        const float i1 = __builtin_amdgcn_rcpf((float)(c1 > 0 ? c1 : 1));
        const float i2 = __builtin_amdgcn_rcpf((float)(c2 > 0 ? c2 : 1));
        const float i3 = __builtin_amdgcn_rcpf((float)(c3 > 0 ? c3 : 1));
        a0 = fmaf(i0, x0.x, a0); a1 = fmaf(i0, x0.y, a1); a2 = fmaf(i0, x0.z, a2); a3 = fmaf(i0, x0.w, a3); aw += i0;
        a0 = fmaf(i1, x1.x, a0); a1 = fmaf(i1, x1.y, a1); a2 = fmaf(i1, x1.z, a2); a3 = fmaf(i1, x1.w, a3); aw += i1;
        a0 = fmaf(i2, x2.x, a0); a1 = fmaf(i2, x2.y, a1); a2 = fmaf(i2, x2.z, a2); a3 = fmaf(i2, x2.w, a3); aw += i2;
        a0 = fmaf(i3, x3.x, a0); a1 = fmaf(i3, x3.y, a1); a2 = fmaf(i3, x3.z, a2); a3 = fmaf(i3, x3.w, a3); aw += i3;
    }
    a0 = wred(a0); a1 = wred(a1); a2 = wred(a2); a3 = wred(a3); aw = wred(aw);
    if ((tid & 63) == 0) {
        float* w5 = lds + (tid >> 6) * 5;
        w5[0] = a0; w5[1] = a1; w5[2] = a2; w5[3] = a3; w5[4] = aw;
    }
    __syncthreads();
    if (tid < 5)
        part[tid] = lds[tid] + lds[5 + tid] + lds[10 + tid] + lds[15 + tid];
}

// ---- main: gine_a | gine_c | sage_tv | sage_log | means ----
template<bool ISF32>
__device__ __forceinline__ void main_body(const Par p, float* smem) {
    const int b = blockIdx.x;
    if (b < B_GA) {
        gine_body<3, 3, ISF32>(p.ei_a, p.ea_a, p.x_m, p.We_a, p.be_a, p.Wm, p.bm,
                               p.part_a + b * H, EA, b, B_GA,
                               smem, smem + 2048, smem + 2304);
    } else if (b < B_GA + B_GC) {
        const int rb = b - B_GA;
        gine_body<4, 1, ISF32>(p.ei_c, p.ea_c, p.x_o, p.We_c, p.be_c, p.Wo, p.bo,
                               p.part_c + rb * H, EC, rb, B_GC,
                               smem, smem + 2048, smem + 2304);
    } else if (b < B_GA + B_GC + B_TV) {
        const int rb = b - (B_GA + B_GC);
        sage_body<ISF32>(p.x_o, p.ei_tv, p.ei_tv + ET, p.cnt_m,
                         p.part_tv + rb * 8, ET, rb, B_TV, smem);
    } else if (b < B_GA + B_GC + B_TV + B_LG) {
        const int rb = b - (B_GA + B_GC + B_TV);
        sage_body<ISF32>(p.x_o, p.ei_log, p.ei_log + EL, p.cnt_o,
                         p.part_lg + rb * 8, EL, rb, B_LG, smem);
    } else {
        const int rb = b - (B_GA + B_GC + B_TV + B_LG);
        if (rb < 8) mean_body<3, ISF32>(p.x_m, p.part_mn + rb * 4, NM, rb, 8, smem);
        else        mean_body<4, ISF32>(p.x_o, p.part_mn + rb * 4, NO, rb - 8, 40, smem);
    }
}

__global__ __launch_bounds__(256) void main_kernel(const Par p) {
    __shared__ __align__(16) float smem[2560];  // 10 KB: stage 8KB + r0/r1 2KB
    if (*p.flag) main_body<true >(p, smem);
    else         main_body<false>(p, smem);
}

// ---- final: reduce partials, reconstruct means, five 128x128 mat-vecs ----
// scal: [0..3]=twx,[4]=tsw,[5..8]=lwx,[9]=lsw,[10..12]=xm,[13..16]=xo
template<bool ISF32>
__device__ __forceinline__ void final_body(const Par p) {
    __shared__ float scal[17];
    __shared__ float segtv[5][8], seglg[5][8];
    __shared__ float sh2a[2][H], sh2c[2][H];
    __shared__ float sha[H], shc[H];
    __shared__ float vtv[H], vmhm[H], va[H], vc[H], vlog[H], vmho[H];
    const int t = threadIdx.x;

    // phase B: column halves (all 256 threads)
    {
        const int col = t & 127, half = t >> 7;
        float sA = 0.f;
        const float* pa = p.part_a + (half * (B_GA / 2)) * H + col;
#pragma unroll 8
        for (int r = 0; r < B_GA / 2; ++r) sA += pa[r * H];
        sh2a[half][col] = sA;
        float sC = 0.f;
        const float* pc = p.part_c + (half * (B_GC / 2)) * H + col;
#pragma unroll 8
        for (int r = 0; r < B_GC / 2; ++r) sC += pc[r * H];
        sh2c[half][col] = sC;
    }
    // phase A: scalar partials, segmented
    if (t < 40) {
        const int k = t >> 3, seg = t & 7;
        float s = 0.f;
        const int r0 = seg * (B_TV / 8);
#pragma unroll 4
        for (int r = r0; r < r0 + B_TV / 8; ++r) s += p.part_tv[r * 8 + k];
        segtv[k][seg] = s;
    } else if (t >= 64 && t < 104) {
        const int k = (t - 64) >> 3, seg = (t - 64) & 7;
        float s = 0.f;
        const int r0 = seg * (B_LG / 8);
#pragma unroll 4
        for (int r = r0; r < r0 + B_LG / 8; ++r) s += p.part_lg[r * 8 + k];
        seglg[k][seg] = s;
    } else if (t >= 128 && t < 131) {
        const int k = t - 128;
        float s = 0.f;
        for (int r = 0; r < 8; ++r) s += p.part_mn[r * 4 + k];
        scal[10 + k] = s;
    } else if (t >= 192 && t < 196) {
        const int k = t - 192;
        float s = 0.f;
#pragma unroll 4
        for (int r = 8; r < 48; ++r) s += p.part_mn[r * 4 + k];
        scal[13 + k] = s;
    }
    __syncthreads();
    if (t < 5) {
        float s = 0.f;
#pragma unroll
        for (int g = 0; g < 8; ++g) s += segtv[t][g];
        scal[t] = s;
    } else if (t >= 64 && t < 69) {
        const int k = t - 64;
        float s = 0.f;
#pragma unroll
        for (int g = 0; g < 8; ++g) s += seglg[k][g];
        scal[5 + k] = s;
    }
    if (t < H) sha[t] = sh2a[0][t] + sh2a[1][t];
    else       shc[t - H] = sh2c[0][t - H] + sh2c[1][t - H];
    __syncthreads();

    if (t < H) {
        float mhm = ldf<ISF32>(p.bm, t);
#pragma unroll
        for (int k = 0; k < 3; ++k)
            mhm = fmaf(scal[10 + k] * (1.f / NM), ldf<ISF32>(p.Wm, k * H + t), mhm);
        float mho = ldf<ISF32>(p.bo, t);
#pragma unroll
        for (int k = 0; k < 4; ++k)
            mho = fmaf(scal[13 + k] * (1.f / NO), ldf<ISF32>(p.Wo, k * H + t), mho);
        float tv = scal[4] * ldf<ISF32>(p.bo, t);
        float lg = scal[9] * ldf<ISF32>(p.bo, t);
#pragma unroll
        for (int k = 0; k < 4; ++k) {
            tv = fmaf(scal[k],     ldf<ISF32>(p.Wo, k * H + t), tv);
            lg = fmaf(scal[5 + k], ldf<ISF32>(p.Wo, k * H + t), lg);
        }
        vmhm[t] = mhm;
        vmho[t] = mho;
        vtv[t]  = tv * (1.f / NM);
        vlog[t] = lg * (1.f / NO);
        va[t] = sha[t] * (1.f / NO) + mho;
        vc[t] = shc[t] * (1.f / NO) + mho;
    }
    __syncthreads();
    float res; int oidx;
    if (t < H) {
        float acc = ldf<ISF32>(p.bl_tv, t);
        for (int k = 0; k < H; ++k) {
            acc = fmaf(vtv[k],  ldf<ISF32>(p.Wl_tv, k * H + t), acc);
            acc = fmaf(vmhm[k], ldf<ISF32>(p.Wr_tv, k * H + t), acc);
        }
        res = acc; oidx = t;
    } else {
        const int c = t - H;
        float acc = ldf<ISF32>(p.bn_a, c) + ldf<ISF32>(p.bn_c, c) + ldf<ISF32>(p.bl_log, c);
        for (int k = 0; k < H; ++k) {
            acc = fmaf(va[k],   ldf<ISF32>(p.Wn_a, k * H + c), acc);
            acc = fmaf(vc[k],   ldf<ISF32>(p.Wn_c, k * H + c), acc);
            acc = fmaf(vlog[k], ldf<ISF32>(p.Wl_log, k * H + c), acc);
            acc = fmaf(vmho[k], ldf<ISF32>(p.Wr_log, k * H + c), acc);
        }
        res = acc * (1.f / 3.f); oidx = H + c;
    }
    if constexpr (ISF32) ((float*)p.out)[oidx] = res;
    else                 ((bf16*)p.out)[oidx] = __float2bfloat16(res);
}

__global__ __launch_bounds__(256) void final_kernel(const Par p) {
    if (*p.flag) final_body<true >(p);
    else         final_body<false>(p);
}

extern "C" void kernel_launch(void* const* d_in, const int* in_sizes, int n_in,
                              void* d_out, int out_size, void* d_ws, size_t ws_size,
                              hipStream_t stream) {
    char* ws = (char*)d_ws;
    Par p;
    p.x_m   = d_in[0];  p.x_o   = d_in[1];
    p.ea_a  = d_in[2];  p.ea_c  = d_in[3];
    p.ei_a  = (const int*)d_in[4];
    p.ei_c  = (const int*)d_in[5];
    p.ei_tv = (const int*)d_in[6];
    p.ei_log= (const int*)d_in[7];
    p.Wm = d_in[8];  p.bm = d_in[9];  p.Wo = d_in[10]; p.bo = d_in[11];
    p.Wn_a = d_in[12]; p.bn_a = d_in[13]; p.We_a = d_in[14]; p.be_a = d_in[15];
    p.Wn_c = d_in[16]; p.bn_c = d_in[17]; p.We_c = d_in[18]; p.be_c = d_in[19];
    p.Wl_tv = d_in[20]; p.bl_tv = d_in[21]; p.Wr_tv = d_in[22];
    p.Wl_log = d_in[23]; p.bl_log = d_in[24]; p.Wr_log = d_in[25];

    // Workspace layout (bytes):
    //   [0,       20480)    cnt_m  int[NM] (padded)
    //   [20480,   421888)   cnt_o  int[NO] (padded)
    //   [421888,  421892)   flag   int
    //   [422144,  684288)   part_a  float[512][128]
    //   [684288,  815360)   part_c  float[256][128]
    //   [815360,  831744)   part_tv float[512][8]
    //   [831744,  839936)   part_lg float[256][8]
    //   [839936,  840704)   part_mn float[48][4]
    p.cnt_m   = (int*)(ws);
    p.cnt_o   = (int*)(ws + 20480);
    p.flagw   = (int*)(ws + 421888);
    p.flag    = p.flagw;
    p.part_a  = (float*)(ws + 422144);
    p.part_c  = (float*)(ws + 684288);
    p.part_tv = (float*)(ws + 815360);
    p.part_lg = (float*)(ws + 831744);
    p.part_mn = (float*)(ws + 839936);
    p.out  = d_out;

    // zero counts + flag: [0, 421892) -> 105473 ints
    const int nzero = 105473;
    zero_kernel<<<(nzero + 255) / 256, 256, 0, stream>>>((int*)ws, nzero);

    aux_kernel<<<AUX_BLOCKS, 256, 0, stream>>>(p);    // detect + counts
    main_kernel<<<MAIN_BLOCKS, 256, 0, stream>>>(p);  // gine + sage + means
    final_kernel<<<1, 256, 0, stream>>>(p);
}

// Round 8
// 239.390 us; speedup vs baseline: 2.0338x; 1.0181x over previous
//
#include <hip/hip_runtime.h>
#include <hip/hip_bf16.h>
#include <stdint.h>

// Problem constants (from reference)
#define H   128
#define NM  5000
#define NO  100000
#define EA  1000000
#define EC  500000
#define ET  1000000
#define EL  500000

typedef __hip_bfloat16 bf16;
typedef float v2f __attribute__((ext_vector_type(2)));

// main kernel partition: gine_a | gine_c | sage_tv | sage_log | means
#define B_GA 512
#define B_GC 256
#define B_TV 512
#define B_LG 256
#define B_MN 48
#define MAIN_BLOCKS (B_GA + B_GC + B_TV + B_LG + B_MN)

// histogram config
#define C_M 32            // cnt_m chunk blocks (full 5000-bin hist each)
#define R_O 8             // cnt_o bin ranges
#define RSZ 12800         // bins per range (8*12800 = 102400 >= NO)
#define C_O 8             // cnt_o edge chunks
#define NOP 102400        // padded cnt_o bins
#define HIST_BLOCKS (1 + C_M + R_O * C_O)
#define MERGE_M_BLK 20    // 5000 bins / 256
#define MERGE_BLOCKS (MERGE_M_BLK + NOP / 256)

struct Par {
    const void *x_m, *x_o, *ea_a, *ea_c;
    const int *ei_a, *ei_c, *ei_tv, *ei_log;
    const void *Wm, *bm, *Wo, *bo;
    const void *Wn_a, *bn_a, *We_a, *be_a;
    const void *Wn_c, *bn_c, *We_c, *be_c;
    const void *Wl_tv, *bl_tv, *Wr_tv, *Wl_log, *bl_log, *Wr_log;
    int *cnt_m, *cnt_o;
    int *part_hm, *part_ho;
    float *part_a, *part_c, *part_tv, *part_lg, *part_mn;
    int *flagw;
    const int *flag;
    void *out;
};

// ---- dtype-flexible loads ----
template<bool ISF32>
__device__ __forceinline__ float ldf(const void* p, int i) {
    if constexpr (ISF32) return ((const float*)p)[i];
    else                 return __bfloat162float(((const bf16*)p)[i]);
}

__device__ __forceinline__ float bflo(uint32_t v) {
    union { uint32_t u; float f; } c; c.u = v << 16; return c.f;
}
__device__ __forceinline__ float bfhi(uint32_t v) {
    union { uint32_t u; float f; } c; c.u = v & 0xFFFF0000u; return c.f;
}

__device__ __forceinline__ uint32_t pack2(float a, float b) {
    union { bf16 h; uint16_t u; } ca, cb;
    ca.h = __float2bfloat16(a); cb.h = __float2bfloat16(b);
    return (uint32_t)ca.u | ((uint32_t)cb.u << 16);
}

template<bool ISF32>
__device__ __forceinline__ float4 ld4(const void* p, int row) {
    if constexpr (ISF32) return ((const float4*)p)[row];
    else {
        const uint2 t = ((const uint2*)p)[row];
        float4 r; r.x = bflo(t.x); r.y = bfhi(t.x); r.z = bflo(t.y); r.w = bfhi(t.y);
        return r;
    }
}

__device__ __forceinline__ float wred(float v) {
#pragma unroll
    for (int o = 32; o; o >>= 1) v += __shfl_down(v, o, 64);
    return v;
}

// ---- phase A: detect + private histograms (NO global atomics) ----
__global__ __launch_bounds__(256) void hist_kernel(const Par p) {
    __shared__ int hist[RSZ];   // 51200 B
    const int t = threadIdx.x;
    const int b = blockIdx.x;
    if (b == 0) {
        // dtype probe: fp32 viewed as u16 contains exponent-0xFF patterns
        int local = 0;
        const uint16_t* xm = (const uint16_t*)p.x_m;
        for (int i = t; i < 15000; i += 256)
            if (((xm[i] >> 7) & 0xFF) == 0xFF) local = 1;
        if (t == 0) hist[0] = 0;
        __syncthreads();
        if (local) atomicOr(&hist[0], 1);
        __syncthreads();
        if (t == 0) *p.flagw = hist[0];
    } else if (b <= C_M) {
        // cnt_m chunk histogram: 5000 bins, chunk of ET/C_M = 31250 edges
        const int c = b - 1;
        for (int i = t; i < NM; i += 256) hist[i] = 0;
        __syncthreads();
        const int2* dst2 = (const int2*)(p.ei_tv + ET);
        const int base = c * (ET / C_M / 2);           // int2 units
        for (int i = t; i < ET / C_M / 2; i += 256) {
            const int2 d = dst2[base + i];
            atomicAdd(&hist[d.x], 1);
            atomicAdd(&hist[d.y], 1);
        }
        __syncthreads();
        int* out = p.part_hm + c * NM;
        for (int i = t; i < NM; i += 256) out[i] = hist[i];
    } else {
        // cnt_o range-filtered histogram: range r, chunk c
        const int idx = b - 1 - C_M;
        const int r = idx / C_O, c = idx % C_O;
        const int lo = r * RSZ;
        for (int i = t; i < RSZ; i += 256) hist[i] = 0;
        __syncthreads();
        const int4* dst4 = (const int4*)(p.ei_log + EL);
        const int base = c * (EL / C_O / 4);           // int4 units
        for (int i = t; i < EL / C_O / 4; i += 256) {
            const int4 d = dst4[base + i];
            unsigned q;
            q = (unsigned)(d.x - lo); if (q < RSZ) atomicAdd(&hist[q], 1);
            q = (unsigned)(d.y - lo); if (q < RSZ) atomicAdd(&hist[q], 1);
            q = (unsigned)(d.z - lo); if (q < RSZ) atomicAdd(&hist[q], 1);
            q = (unsigned)(d.w - lo); if (q < RSZ) atomicAdd(&hist[q], 1);
        }
        __syncthreads();
        int* out = p.part_ho + c * NOP + lo;
        for (int i = t; i < RSZ; i += 256) out[i] = hist[i];
    }
}

// ---- phase B: merge histograms -> counts (plain coalesced stores) ----
__global__ __launch_bounds__(256) void merge_kernel(const Par p) {
    const int t = threadIdx.x;
    const int b = blockIdx.x;
    if (b < MERGE_M_BLK) {
        const int bin = b * 256 + t;
        if (bin < NM) {
            int s = 0;
#pragma unroll 8
            for (int c = 0; c < C_M; ++c) s += p.part_hm[c * NM + bin];
            p.cnt_m[bin] = s;
        }
    } else {
        const int bin = (b - MERGE_M_BLK) * 256 + t;   // < NOP
        int s = 0;
#pragma unroll
        for (int c = 0; c < C_O; ++c) s += p.part_ho[c * NOP + bin];
        p.cnt_o[bin] = s;
    }
}

// ---- GINE: coalesced stage -> bf16-packed LDS (1 read/edge) -> pk math ----
template<int FIN, int ED, bool ISF32>
__device__ __forceinline__ void gine_body(
    const int* __restrict__ src, const void* __restrict__ ea,
    const void* __restrict__ x, const void* __restrict__ We,
    const void* __restrict__ be, const void* __restrict__ Wx,
    const void* __restrict__ bx, float* __restrict__ part,
    int E, int relb, int nblk, uint4* stage, float* r0, float* r1)
{
    constexpr int KT = FIN + ED;     // <= 7
    const int lane = threadIdx.x & 63;
    const int wv = threadIdx.x >> 6;
    const int c0 = 2 * lane;
    v2f wc[KT];
#pragma unroll
    for (int k = 0; k < FIN; ++k)
        wc[k] = (v2f){ldf<ISF32>(Wx, k * H + c0), ldf<ISF32>(Wx, k * H + c0 + 1)};
#pragma unroll
    for (int k = 0; k < ED; ++k)
        wc[FIN + k] = (v2f){ldf<ISF32>(We, k * H + c0), ldf<ISF32>(We, k * H + c0 + 1)};
    const v2f bb = (v2f){ldf<ISF32>(bx, c0) + ldf<ISF32>(be, c0),
                         ldf<ISF32>(bx, c0 + 1) + ldf<ISF32>(be, c0 + 1)};

    uint4* myst = stage + wv * 64;

    v2f acc = (v2f){0.f, 0.f};
    const int G = (E + 63) >> 6;
    const int NW = nblk * 4;
    for (int g = relb * 4 + wv; g < G; g += NW) {
        const int base = g << 6;
        const int ecnt = min(64, E - base);
        const int ej = base + (lane < ecnt ? lane : ecnt - 1);
        float f[8];
#pragma unroll
        for (int k = 0; k < 8; ++k) f[k] = 0.f;
        const int s = src[ej];
        if constexpr (FIN == 4) {
            const float4 xv = ld4<ISF32>(x, s);
            f[0] = xv.x; f[1] = xv.y; f[2] = xv.z; f[3] = xv.w;
        } else {
#pragma unroll
            for (int k = 0; k < FIN; ++k) f[k] = ldf<ISF32>(x, s * FIN + k);
        }
#pragma unroll
        for (int k = 0; k < ED; ++k) f[FIN + k] = ldf<ISF32>(ea, ej * ED + k);
        uint4 pk;
        pk.x = pack2(f[0], f[1]); pk.y = pack2(f[2], f[3]);
        pk.z = pack2(f[4], f[5]); pk.w = pack2(f[6], f[7]);
        myst[lane] = pk;   // DS ops in-order within wave: later reads see this
        // broadcast-compute over staged edges (1 ds_read_b128 per edge)
#pragma unroll 2
        for (int jj = 0; jj < ecnt; ++jj) {
            const uint4 u = myst[jj];
            float fe[8];
            fe[0] = bflo(u.x); fe[1] = bfhi(u.x);
            fe[2] = bflo(u.y); fe[3] = bfhi(u.y);
            if constexpr (KT > 4) { fe[4] = bflo(u.z); fe[5] = bfhi(u.z); }
            if constexpr (KT > 6) { fe[6] = bflo(u.w); fe[7] = bfhi(u.w); }
            v2f m = bb;
#pragma unroll
            for (int k = 0; k < KT; ++k)
                m += wc[k] * (v2f){fe[k], fe[k]};
            m.x = fmaxf(m.x, 0.f);
            m.y = fmaxf(m.y, 0.f);
            acc += m;
        }
    }
    r0[threadIdx.x] = acc.x; r1[threadIdx.x] = acc.y;
    __syncthreads();
    if (threadIdx.x < 64) {
        const int l = threadIdx.x;
        float s0 = r0[l] + r0[l + 64] + r0[l + 128] + r0[l + 192];
        float s1 = r1[l] + r1[l + 64] + r1[l + 128] + r1[l + 192];
        part[2 * l]     = s0;
        part[2 * l + 1] = s1;
    }
}

// ---- component sums of x over nodes ----
template<int FIN, bool ISF32>
__device__ __forceinline__ void mean_body(
    const void* __restrict__ x, float* __restrict__ part, int N,
    int relb, int nblk, float* lds)
{
    const int stride = nblk * 256;
    float acc[FIN];
#pragma unroll
    for (int k = 0; k < FIN; ++k) acc[k] = 0.f;
    for (int n = relb * 256 + threadIdx.x; n < N; n += stride) {
        if constexpr (FIN == 4) {
            const float4 xv = ld4<ISF32>(x, n);
            acc[0] += xv.x; acc[1] += xv.y; acc[2] += xv.z; acc[3] += xv.w;
        } else {
#pragma unroll
            for (int k = 0; k < FIN; ++k) acc[k] += ldf<ISF32>(x, n * FIN + k);
        }
    }
#pragma unroll
    for (int k = 0; k < FIN; ++k) acc[k] = wred(acc[k]);
    if ((threadIdx.x & 63) == 0) {
        const int w = threadIdx.x >> 6;
#pragma unroll
        for (int k = 0; k < 4; ++k) lds[w * 4 + k] = (k < FIN) ? acc[k] : 0.f;
    }
    __syncthreads();
    if (threadIdx.x < 4)
        part[threadIdx.x] = lds[threadIdx.x] + lds[4 + threadIdx.x]
                          + lds[8 + threadIdx.x] + lds[12 + threadIdx.x];
}

// ---- SAGE edge reduction, int4-batched ----
template<bool ISF32>
__device__ __forceinline__ void sage_body(
    const void* __restrict__ x, const int* __restrict__ src,
    const int* __restrict__ dst, const int* __restrict__ cnt,
    float* __restrict__ part, int E, int relb, int nblk, float* lds)
{
    const int tid = threadIdx.x;
    const int nv = E >> 2;
    const int stride = nblk * 256;
    float a0 = 0.f, a1 = 0.f, a2 = 0.f, a3 = 0.f, aw = 0.f;
#pragma unroll 2
    for (int i = relb * 256 + tid; i < nv; i += stride) {
        const int4 s4 = ((const int4*)src)[i];
        const int4 d4 = ((const int4*)dst)[i];
        const int c0 = cnt[d4.x], c1 = cnt[d4.y], c2 = cnt[d4.z], c3 = cnt[d4.w];
        const float4 x0 = ld4<ISF32>(x, s4.x);
        const float4 x1 = ld4<ISF32>(x, s4.y);
        const float4 x2 = ld4<ISF32>(x, s4.z);
        const float4 x3 = ld4<ISF32>(x, s4.w);
        const float i0 = __builtin_amdgcn_rcpf((float)(c0 > 0 ? c0 : 1));
        const float i1 = __builtin_amdgcn_rcpf((float)(c1 > 0 ? c1 : 1));
        const float i2 = __builtin_amdgcn_rcpf((float)(c2 > 0 ? c2 : 1));
        const float i3 = __builtin_amdgcn_rcpf((float)(c3 > 0 ? c3 : 1));
        a0 = fmaf(i0, x0.x, a0); a1 = fmaf(i0, x0.y, a1); a2 = fmaf(i0, x0.z, a2); a3 = fmaf(i0, x0.w, a3); aw += i0;
        a0 = fmaf(i1, x1.x, a0); a1 = fmaf(i1, x1.y, a1); a2 = fmaf(i1, x1.z, a2); a3 = fmaf(i1, x1.w, a3); aw += i1;
        a0 = fmaf(i2, x2.x, a0); a1 = fmaf(i2, x2.y, a1); a2 = fmaf(i2, x2.z, a2); a3 = fmaf(i2, x2.w, a3); aw += i2;
        a0 = fmaf(i3, x3.x, a0); a1 = fmaf(i3, x3.y, a1); a2 = fmaf(i3, x3.z, a2); a3 = fmaf(i3, x3.w, a3); aw += i3;
    }
    a0 = wred(a0); a1 = wred(a1); a2 = wred(a2); a3 = wred(a3); aw = wred(aw);
    if ((tid & 63) == 0) {
        float* w5 = lds + (tid >> 6) * 5;
        w5[0] = a0; w5[1] = a1; w5[2] = a2; w5[3] = a3; w5[4] = aw;
    }
    __syncthreads();
    if (tid < 5)
        part[tid] = lds[tid] + lds[5 + tid] + lds[10 + tid] + lds[15 + tid];
}

// ---- main: gine_a | gine_c | sage_tv | sage_log | means ----
template<bool ISF32>
__device__ __forceinline__ void main_body(const Par p, uint4* stage, float* red) {
    const int b = blockIdx.x;
    if (b < B_GA) {
        gine_body<3, 3, ISF32>(p.ei_a, p.ea_a, p.x_m, p.We_a, p.be_a, p.Wm, p.bm,
                               p.part_a + b * H, EA, b, B_GA,
                               stage, red, red + 256);
    } else if (b < B_GA + B_GC) {
        const int rb = b - B_GA;
        gine_body<4, 1, ISF32>(p.ei_c, p.ea_c, p.x_o, p.We_c, p.be_c, p.Wo, p.bo,
                               p.part_c + rb * H, EC, rb, B_GC,
                               stage, red, red + 256);
    } else if (b < B_GA + B_GC + B_TV) {
        const int rb = b - (B_GA + B_GC);
        sage_body<ISF32>(p.x_o, p.ei_tv, p.ei_tv + ET, p.cnt_m,
                         p.part_tv + rb * 8, ET, rb, B_TV, red);
    } else if (b < B_GA + B_GC + B_TV + B_LG) {
        const int rb = b - (B_GA + B_GC + B_TV);
        sage_body<ISF32>(p.x_o, p.ei_log, p.ei_log + EL, p.cnt_o,
                         p.part_lg + rb * 8, EL, rb, B_LG, red);
    } else {
        const int rb = b - (B_GA + B_GC + B_TV + B_LG);
        if (rb < 8) mean_body<3, ISF32>(p.x_m, p.part_mn + rb * 4, NM, rb, 8, red);
        else        mean_body<4, ISF32>(p.x_o, p.part_mn + rb * 4, NO, rb - 8, 40, red);
    }
}

__global__ __launch_bounds__(256) void main_kernel(const Par p) {
    __shared__ __align__(16) uint4 stage[256];   // 4 KB: 4 waves x 64 edges
    __shared__ float red[512 + 32];
    if (*p.flag) main_body<true >(p, stage, red);
    else         main_body<false>(p, stage, red);
}

// ---- final: reduce partials, reconstruct means, five 128x128 mat-vecs ----
// scal: [0..3]=twx,[4]=tsw,[5..8]=lwx,[9]=lsw,[10..12]=xm,[13..16]=xo
template<bool ISF32>
__device__ __forceinline__ void final_body(const Par p) {
    __shared__ float scal[17];
    __shared__ float segtv[5][8], seglg[5][8];
    __shared__ float sh2a[2][H], sh2c[2][H];
    __shared__ float sha[H], shc[H];
    __shared__ float vtv[H], vmhm[H], va[H], vc[H], vlog[H], vmho[H];
    const int t = threadIdx.x;

    // phase B: column halves (all 256 threads)
    {
        const int col = t & 127, half = t >> 7;
        float sA = 0.f;
        const float* pa = p.part_a + (half * (B_GA / 2)) * H + col;
#pragma unroll 8
        for (int r = 0; r < B_GA / 2; ++r) sA += pa[r * H];
        sh2a[half][col] = sA;
        float sC = 0.f;
        const float* pc = p.part_c + (half * (B_GC / 2)) * H + col;
#pragma unroll 8
        for (int r = 0; r < B_GC / 2; ++r) sC += pc[r * H];
        sh2c[half][col] = sC;
    }
    // phase A: scalar partials, segmented
    if (t < 40) {
        const int k = t >> 3, seg = t & 7;
        float s = 0.f;
        const int r0 = seg * (B_TV / 8);
#pragma unroll 4
        for (int r = r0; r < r0 + B_TV / 8; ++r) s += p.part_tv[r * 8 + k];
        segtv[k][seg] = s;
    } else if (t >= 64 && t < 104) {
        const int k = (t - 64) >> 3, seg = (t - 64) & 7;
        float s = 0.f;
        const int r0 = seg * (B_LG / 8);
#pragma unroll 4
        for (int r = r0; r < r0 + B_LG / 8; ++r) s += p.part_lg[r * 8 + k];
        seglg[k][seg] = s;
    } else if (t >= 128 && t < 131) {
        const int k = t - 128;
        float s = 0.f;
        for (int r = 0; r < 8; ++r) s += p.part_mn[r * 4 + k];
        scal[10 + k] = s;
    } else if (t >= 192 && t < 196) {
        const int k = t - 192;
        float s = 0.f;
#pragma unroll 4
        for (int r = 8; r < 48; ++r) s += p.part_mn[r * 4 + k];
        scal[13 + k] = s;
    }
    __syncthreads();
    if (t < 5) {
        float s = 0.f;
#pragma unroll
        for (int g = 0; g < 8; ++g) s += segtv[t][g];
        scal[t] = s;
    } else if (t >= 64 && t < 69) {
        const int k = t - 64;
        float s = 0.f;
#pragma unroll
        for (int g = 0; g < 8; ++g) s += seglg[k][g];
        scal[5 + k] = s;
    }
    if (t < H) sha[t] = sh2a[0][t] + sh2a[1][t];
    else       shc[t - H] = sh2c[0][t - H] + sh2c[1][t - H];
    __syncthreads();

    if (t < H) {
        float mhm = ldf<ISF32>(p.bm, t);
#pragma unroll
        for (int k = 0; k < 3; ++k)
            mhm = fmaf(scal[10 + k] * (1.f / NM), ldf<ISF32>(p.Wm, k * H + t), mhm);
        float mho = ldf<ISF32>(p.bo, t);
#pragma unroll
        for (int k = 0; k < 4; ++k)
            mho = fmaf(scal[13 + k] * (1.f / NO), ldf<ISF32>(p.Wo, k * H + t), mho);
        float tv = scal[4] * ldf<ISF32>(p.bo, t);
        float lg = scal[9] * ldf<ISF32>(p.bo, t);
#pragma unroll
        for (int k = 0; k < 4; ++k) {
            tv = fmaf(scal[k],     ldf<ISF32>(p.Wo, k * H + t), tv);
            lg = fmaf(scal[5 + k], ldf<ISF32>(p.Wo, k * H + t), lg);
        }
        vmhm[t] = mhm;
        vmho[t] = mho;
        vtv[t]  = tv * (1.f / NM);
        vlog[t] = lg * (1.f / NO);
        va[t] = sha[t] * (1.f / NO) + mho;
        vc[t] = shc[t] * (1.f / NO) + mho;
    }
    __syncthreads();
    float res; int oidx;
    if (t < H) {
        float acc = ldf<ISF32>(p.bl_tv, t);
        for (int k = 0; k < H; ++k) {
            acc = fmaf(vtv[k],  ldf<ISF32>(p.Wl_tv, k * H + t), acc);
            acc = fmaf(vmhm[k], ldf<ISF32>(p.Wr_tv, k * H + t), acc);
        }
        res = acc; oidx = t;
    } else {
        const int c = t - H;
        float acc = ldf<ISF32>(p.bn_a, c) + ldf<ISF32>(p.bn_c, c) + ldf<ISF32>(p.bl_log, c);
        for (int k = 0; k < H; ++k) {
            acc = fmaf(va[k],   ldf<ISF32>(p.Wn_a, k * H + c), acc);
            acc = fmaf(vc[k],   ldf<ISF32>(p.Wn_c, k * H + c), acc);
            acc = fmaf(vlog[k], ldf<ISF32>(p.Wl_log, k * H + c), acc);
            acc = fmaf(vmho[k], ldf<ISF32>(p.Wr_log, k * H + c), acc);
        }
        res = acc * (1.f / 3.f); oidx = H + c;
    }
    if constexpr (ISF32) ((float*)p.out)[oidx] = res;
    else                 ((bf16*)p.out)[oidx] = __float2bfloat16(res);
}

__global__ __launch_bounds__(256) void final_kernel(const Par p) {
    if (*p.flag) final_body<true >(p);
    else         final_body<false>(p);
}

extern "C" void kernel_launch(void* const* d_in, const int* in_sizes, int n_in,
                              void* d_out, int out_size, void* d_ws, size_t ws_size,
                              hipStream_t stream) {
    char* ws = (char*)d_ws;
    Par p;
    p.x_m   = d_in[0];  p.x_o   = d_in[1];
    p.ea_a  = d_in[2];  p.ea_c  = d_in[3];
    p.ei_a  = (const int*)d_in[4];
    p.ei_c  = (const int*)d_in[5];
    p.ei_tv = (const int*)d_in[6];
    p.ei_log= (const int*)d_in[7];
    p.Wm = d_in[8];  p.bm = d_in[9];  p.Wo = d_in[10]; p.bo = d_in[11];
    p.Wn_a = d_in[12]; p.bn_a = d_in[13]; p.We_a = d_in[14]; p.be_a = d_in[15];
    p.Wn_c = d_in[16]; p.bn_c = d_in[17]; p.We_c = d_in[18]; p.be_c = d_in[19];
    p.Wl_tv = d_in[20]; p.bl_tv = d_in[21]; p.Wr_tv = d_in[22];
    p.Wl_log = d_in[23]; p.bl_log = d_in[24]; p.Wr_log = d_in[25];

    // Workspace layout (bytes), all regions fully written by their owners
    // (no zero kernel needed):
    //   [0,        20480)    cnt_m   int[5000] (padded)
    //   [20480,    430080)   cnt_o   int[102400]
    //   [430080,   430084)   flag    int (plain store by hist block 0)
    //   [430592,   1070592)  part_hm int[32][5000]
    //   [1070592,  4347392)  part_ho int[8][102400]  (chunk-major)
    //   [4347392,  4609536)  part_a  float[512][128]
    //   [4609536,  4740608)  part_c  float[256][128]
    //   [4740608,  4756992)  part_tv float[512][8]
    //   [4756992,  4765184)  part_lg float[256][8]
    //   [4765184,  4765952)  part_mn float[48][4]
    p.cnt_m   = (int*)(ws);
    p.cnt_o   = (int*)(ws + 20480);
    p.flagw   = (int*)(ws + 430080);
    p.flag    = p.flagw;
    p.part_hm = (int*)(ws + 430592);
    p.part_ho = (int*)(ws + 1070592);
    p.part_a  = (float*)(ws + 4347392);
    p.part_c  = (float*)(ws + 4609536);
    p.part_tv = (float*)(ws + 4740608);
    p.part_lg = (float*)(ws + 4756992);
    p.part_mn = (float*)(ws + 4765184);
    p.out  = d_out;

    hist_kernel<<<HIST_BLOCKS, 256, 0, stream>>>(p);    // detect + private hists
    merge_kernel<<<MERGE_BLOCKS, 256, 0, stream>>>(p);  // counts (atomic-free)
    main_kernel<<<MAIN_BLOCKS, 256, 0, stream>>>(p);    // gine + sage + means
    final_kernel<<<1, 256, 0, stream>>>(p);
}